// Round 6
// baseline (275.759 us; speedup 1.0000x reference)
//
#include <hip/hip_runtime.h>
#include <hip/hip_bf16.h>

typedef __hip_bfloat16 bf16;
typedef __attribute__((ext_vector_type(8))) short sh8;
typedef __attribute__((ext_vector_type(4))) float f32x4;

// Problem constants
#define BB 2
#define TT 2048
#define EE 1024
#define NH 16
#define HD 64
#define M_ROWS (BB * TT)          // 4096
#define PPAD 72                   // P-tile LDS row stride (elements)

__device__ __forceinline__ float b2f(bf16 v) { return __bfloat162float(v); }
__device__ __forceinline__ bf16 f2b(float v) { return __float2bfloat16(v); }
__device__ __forceinline__ unsigned short f2bu(float v) {
    union { bf16 b; unsigned short u; } x; x.b = f2b(v); return x.u;
}

// async global->LDS, 16B per lane: LDS gets (firstlane base) + lane*16.
__device__ __forceinline__ void gl2lds16(const bf16* g, bf16* l) {
    __builtin_amdgcn_global_load_lds(
        (__attribute__((address_space(1))) void*)g,
        (__attribute__((address_space(3))) void*)l, 16, 0, 0);
}

// ---------------------------------------------------------------------------
// Merged prep: block ranges
//   [0, 4096)        cast x (f32->bf16), 4 elems/thread
//   [4096, 4864)     transpose-cast w_qkv  [1024,3072] -> [3072,1024] bf16
//   [4864, 5120)     transpose-cast w_proj [1024,1024] -> [1024,1024] bf16
// ---------------------------------------------------------------------------
__global__ __launch_bounds__(256) void prep(
    const float* __restrict__ x, bf16* __restrict__ xb,
    const float* __restrict__ Wq, bf16* __restrict__ Wqt,
    const float* __restrict__ Wp, bf16* __restrict__ Wpt) {
    const int bid = blockIdx.x;
    if (bid < 4096) {
        const int i = bid * 256 + threadIdx.x;
        const float4 v = ((const float4*)x)[i];
        ushort4 u;
        u.x = f2bu(v.x); u.y = f2bu(v.y); u.z = f2bu(v.z); u.w = f2bu(v.w);
        ((ushort4*)xb)[i] = u;
        return;
    }
    __shared__ float Ld[64][65];
    const float* src; bf16* dst; int ncols, nc0, kr0;
    if (bid < 4096 + 768) {
        const int t = bid - 4096;
        src = Wq; dst = Wqt; ncols = 3072;
        nc0 = (t % 48) * 64; kr0 = (t / 48) * 64;
    } else {
        const int t = bid - 4096 - 768;
        src = Wp; dst = Wpt; ncols = 1024;
        nc0 = (t % 16) * 64; kr0 = (t / 16) * 64;
    }
#pragma unroll
    for (int i = 0; i < 16; ++i) {
        const int e = threadIdx.x + i * 256;
        Ld[e >> 6][e & 63] = src[(size_t)(kr0 + (e >> 6)) * ncols + nc0 + (e & 63)];
    }
    __syncthreads();
#pragma unroll
    for (int i = 0; i < 16; ++i) {
        const int e = threadIdx.x + i * 256;
        const int r2 = e & 63, c2 = e >> 6;
        dst[(size_t)(nc0 + c2) * EE + kr0 + r2] = f2b(Ld[r2][c2]);
    }
}

// ---------------------------------------------------------------------------
// MFMA GEMM core (128x128 2-phase) -- retained for the output projection.
// ---------------------------------------------------------------------------
__device__ __forceinline__ void mfma_gemm_core(
    const bf16* __restrict__ A, const bf16* __restrict__ Bt,
    int m0, int n0, f32x4 acc[4][4], bf16* Al, bf16* Bl) {
    const int tid = threadIdx.x, w = tid >> 6, lane = tid & 63;
    const int li = lane & 15, quad = lane >> 4;
    const int wm = (w & 1) * 64, wn = (w >> 1) * 64;
    const int srow = w * 32 + (lane >> 3);
    const int scol = (lane & 7) * 8;

#pragma unroll
    for (int mt = 0; mt < 4; ++mt)
#pragma unroll
        for (int nt = 0; nt < 4; ++nt) acc[mt][nt] = (f32x4){0.f, 0.f, 0.f, 0.f};

    for (int k0 = 0; k0 < EE; k0 += 64) {
        __syncthreads();
#pragma unroll
        for (int j = 0; j < 4; ++j) {
            const int row = srow + j * 8;
            const int sk = scol ^ ((row & 7) * 8);
            gl2lds16(A  + (size_t)(m0 + row) * EE + k0 + sk, Al + row * 64 + scol);
            gl2lds16(Bt + (size_t)(n0 + row) * EE + k0 + sk, Bl + row * 64 + scol);
        }
        __syncthreads();
#pragma unroll
        for (int ks = 0; ks < 2; ++ks) {
            const int kof = (ks * 32 + quad * 8) ^ ((li & 7) * 8);
            sh8 af[4], bv[4];
#pragma unroll
            for (int mt = 0; mt < 4; ++mt)
                af[mt] = *(const sh8*)(Al + (wm + mt * 16 + li) * 64 + kof);
#pragma unroll
            for (int nt = 0; nt < 4; ++nt)
                bv[nt] = *(const sh8*)(Bl + (wn + nt * 16 + li) * 64 + kof);
#pragma unroll
            for (int mt = 0; mt < 4; ++mt)
#pragma unroll
                for (int nt = 0; nt < 4; ++nt)
                    acc[mt][nt] = __builtin_amdgcn_mfma_f32_16x16x32_bf16(
                        af[mt], bv[nt], acc[mt][nt], 0, 0, 0);
        }
    }
}

// ---------------------------------------------------------------------------
// QKV GEMM, 8-phase 256x256 schedule (T2 swizzle + T3/T4 counted vmcnt + T5).
// 512 threads = 8 waves (2M x 4N); per-wave 128x64 output (8x4 16x16 frags).
// LDS: 2 dbuf x (A 256x64 + B 256x64) bf16 = 128 KiB. BK=64, 16 K-tiles.
// Zig-zag quadrant order Q00->Q01->Q11->Q10 so each operand half dies one
// phase after load (max live fragments 64 VGPR). Stage slots:
//   p1 A(2i+1,0)  p2 A(2i+1,1)  p3 B(2i+2,0)  p4 B(2i+2,1)+vm4
//   p5 A(2i+2,0)  p6 A(2i+2,1)  p7 B(2i+3,0)  p8 B(2i+3,1)+vm4
// Q is pre-scaled by 0.125 in the epilogue (folded attention scale).
// ---------------------------------------------------------------------------
#define QBM 256
#define QBN 256
#define QBK 64
#define QNT (EE / QBK)   // 16 K-tiles

__global__ __launch_bounds__(512, 2) void gemm_qkv_8ph(
    const bf16* __restrict__ A, const bf16* __restrict__ Bt,
    const float* __restrict__ bias,
    bf16* __restrict__ Qb, bf16* __restrict__ Kb, bf16* __restrict__ Vb) {
    __shared__ bf16 Al[2][QBM * QBK];   // 64 KiB
    __shared__ bf16 Bl[2][QBN * QBK];   // 64 KiB

    const int tid  = threadIdx.x;
    const int lane = tid & 63;
    const int w    = tid >> 6;
    const int li   = lane & 15, quad = lane >> 4;
    const int wr   = w >> 2, wc = w & 3;       // 2 x 4 wave grid
    const int wm   = wr << 7, wn = wc << 6;    // wave origin in tile
    const int m0   = blockIdx.y << 8, n0 = blockIdx.x << 8;

    // staging geometry: thread covers (row = h*128 + j*64 + tid/8, col = (tid&7)*8)
    const int srow = tid >> 3;
    const int scol = (tid & 7) << 3;
    const int sg   = scol ^ ((srow & 7) << 3);   // pre-swizzled global col
    // read-side swizzle
    const int swz  = (li & 7) << 3;
    const int kof0 = (quad << 3) ^ swz;
    const int kof1 = (32 + (quad << 3)) ^ swz;

    f32x4 acc[8][4];
#pragma unroll
    for (int m = 0; m < 8; ++m)
#pragma unroll
        for (int n = 0; n < 4; ++n) acc[m][n] = (f32x4){0.f, 0.f, 0.f, 0.f};

    sh8 ra[4][2];    // current A-half frags (reused half0/half1)
    sh8 rb0[2][2];   // B-half0 frags
    sh8 rb1[2][2];   // B-half1 frags

#define QSTAGE_A(t, h) do {                                                    \
        const int _k0 = (t) * QBK; bf16* _lb = &Al[(t) & 1][0];                \
        _Pragma("unroll")                                                      \
        for (int _j = 0; _j < 2; ++_j) {                                       \
            const int _r = ((h) << 7) + (_j << 6) + srow;                      \
            gl2lds16(A + (size_t)(m0 + _r) * EE + _k0 + sg,                    \
                     _lb + _r * QBK + scol);                                   \
        }                                                                      \
    } while (0)

#define QSTAGE_B(t, h) do {                                                    \
        const int _k0 = (t) * QBK; bf16* _lb = &Bl[(t) & 1][0];                \
        _Pragma("unroll")                                                      \
        for (int _j = 0; _j < 2; ++_j) {                                       \
            const int _r = ((h) << 7) + (_j << 6) + srow;                      \
            gl2lds16(Bt + (size_t)(n0 + _r) * EE + _k0 + sg,                   \
                     _lb + _r * QBK + scol);                                   \
        }                                                                      \
    } while (0)

#define QLOAD_A(cb, a) do {                                                    \
        const bf16* _ab = &Al[cb][0];                                          \
        _Pragma("unroll")                                                      \
        for (int _m = 0; _m < 4; ++_m) {                                       \
            const int _row = wm + (((a) << 2) + _m) * 16 + li;                 \
            ra[_m][0] = *(const sh8*)(_ab + _row * QBK + kof0);                \
            ra[_m][1] = *(const sh8*)(_ab + _row * QBK + kof1);                \
        }                                                                      \
    } while (0)

#define QLOAD_B(cb, b, R) do {                                                 \
        const bf16* _bb = &Bl[cb][0];                                          \
        _Pragma("unroll")                                                      \
        for (int _n = 0; _n < 2; ++_n) {                                       \
            const int _row = wn + (((b) << 1) + _n) * 16 + li;                 \
            R[_n][0] = *(const sh8*)(_bb + _row * QBK + kof0);                 \
            R[_n][1] = *(const sh8*)(_bb + _row * QBK + kof1);                 \
        }                                                                      \
    } while (0)

// one C-quadrant x K=64: 16 MFMA
#define QMFMA(a, b, R) do {                                                    \
        _Pragma("unroll")                                                      \
        for (int _m = 0; _m < 4; ++_m)                                         \
            _Pragma("unroll")                                                  \
            for (int _n = 0; _n < 2; ++_n) {                                   \
                acc[((a) << 2) + _m][((b) << 1) + _n] =                        \
                    __builtin_amdgcn_mfma_f32_16x16x32_bf16(                   \
                        ra[_m][0], R[_n][0],                                   \
                        acc[((a) << 2) + _m][((b) << 1) + _n], 0, 0, 0);       \
                acc[((a) << 2) + _m][((b) << 1) + _n] =                        \
                    __builtin_amdgcn_mfma_f32_16x16x32_bf16(                   \
                        ra[_m][1], R[_n][1],                                   \
                        acc[((a) << 2) + _m][((b) << 1) + _n], 0, 0, 0);       \
            }                                                                  \
    } while (0)

#define PH_MID() do { __builtin_amdgcn_s_barrier();                            \
        asm volatile("s_waitcnt lgkmcnt(0)" ::: "memory");                     \
        __builtin_amdgcn_s_setprio(1); } while (0)
#define PH_END() do { __builtin_amdgcn_s_setprio(0);                           \
        __builtin_amdgcn_s_barrier(); } while (0)
#define PH_END_VM4() do { __builtin_amdgcn_s_setprio(0);                       \
        asm volatile("s_waitcnt vmcnt(4)" ::: "memory");                       \
        __builtin_amdgcn_s_barrier(); } while (0)
#define PH_END_VM0() do { __builtin_amdgcn_s_setprio(0);                       \
        asm volatile("s_waitcnt vmcnt(0)" ::: "memory");                       \
        __builtin_amdgcn_s_barrier(); } while (0)

    // prologue: tile0 A+B (8 loads) + B(1) (4 loads); vm4 => tile0 landed
    QSTAGE_A(0, 0); QSTAGE_A(0, 1); QSTAGE_B(0, 0); QSTAGE_B(0, 1);
    QSTAGE_B(1, 0); QSTAGE_B(1, 1);
    asm volatile("s_waitcnt vmcnt(4)" ::: "memory");
    __builtin_amdgcn_s_barrier();

#pragma unroll 1
    for (int i = 0; i < QNT / 2 - 1; ++i) {
        const int ta = 2 * i + 1, tb = 2 * i + 2, tc = 2 * i + 3;
        // ---- tile 2i (buf0): zig-zag Q00,Q01,Q11,Q10 ----
        QLOAD_A(0, 0); QLOAD_B(0, 0, rb0); QSTAGE_A(ta, 0);   // p1
        PH_MID(); QMFMA(0, 0, rb0); PH_END();
        QLOAD_B(0, 1, rb1); QSTAGE_A(ta, 1);                  // p2
        PH_MID(); QMFMA(0, 1, rb1); PH_END();
        QLOAD_A(0, 1); QSTAGE_B(tb, 0);                       // p3
        PH_MID(); QMFMA(1, 1, rb1); PH_END();
        QSTAGE_B(tb, 1);                                      // p4
        PH_MID(); QMFMA(1, 0, rb0); PH_END_VM4();
        // ---- tile 2i+1 (buf1) ----
        QLOAD_A(1, 0); QLOAD_B(1, 0, rb0); QSTAGE_A(tb, 0);   // p5
        PH_MID(); QMFMA(0, 0, rb0); PH_END();
        QLOAD_B(1, 1, rb1); QSTAGE_A(tb, 1);                  // p6
        PH_MID(); QMFMA(0, 1, rb1); PH_END();
        QLOAD_A(1, 1); QSTAGE_B(tc, 0);                       // p7
        PH_MID(); QMFMA(1, 1, rb1); PH_END();
        QSTAGE_B(tc, 1);                                      // p8
        PH_MID(); QMFMA(1, 0, rb0); PH_END_VM4();
    }

    // epilogue: tile 14 (buf0) staging A(15); tile 15 (buf1), no stages
    QLOAD_A(0, 0); QLOAD_B(0, 0, rb0); QSTAGE_A(QNT - 1, 0);  // p1
    PH_MID(); QMFMA(0, 0, rb0); PH_END();
    QLOAD_B(0, 1, rb1); QSTAGE_A(QNT - 1, 1);                 // p2
    PH_MID(); QMFMA(0, 1, rb1); PH_END();
    QLOAD_A(0, 1);                                            // p3
    PH_MID(); QMFMA(1, 1, rb1); PH_END();
    PH_MID(); QMFMA(1, 0, rb0); PH_END_VM0();                 // p4
    QLOAD_A(1, 0); QLOAD_B(1, 0, rb0);                        // p5
    PH_MID(); QMFMA(0, 0, rb0); PH_END();
    QLOAD_B(1, 1, rb1);                                       // p6
    PH_MID(); QMFMA(0, 1, rb1); PH_END();
    QLOAD_A(1, 1);                                            // p7
    PH_MID(); QMFMA(1, 1, rb1); PH_END();
    PH_MID(); QMFMA(1, 0, rb0);                               // p8
    __builtin_amdgcn_s_setprio(0);

#undef QSTAGE_A
#undef QSTAGE_B
#undef QLOAD_A
#undef QLOAD_B
#undef QMFMA
#undef PH_MID
#undef PH_END
#undef PH_END_VM4
#undef PH_END_VM0

    // ---- C-write: scatter into Q (x0.125), K, or V-transposed ----
    const int which = n0 >> 10;   // 0=Q, 1=K, 2=V (256 | 1024, no straddle)
#pragma unroll
    for (int nt = 0; nt < 4; ++nt) {
        const int n = n0 + wn + nt * 16 + li;
        const int hseg = n & 1023;
        const int h = hseg >> 6, d = hseg & 63;
        const float bv = bias[n];
        if (which == 2) {
#pragma unroll
            for (int mt = 0; mt < 8; ++mt) {
                const int mb = m0 + wm + mt * 16 + quad * 4;
                const int b = mb >> 11, t = mb & (TT - 1);
                ushort4 u;
                u.x = f2bu(acc[mt][nt][0] + bv);
                u.y = f2bu(acc[mt][nt][1] + bv);
                u.z = f2bu(acc[mt][nt][2] + bv);
                u.w = f2bu(acc[mt][nt][3] + bv);
                *(ushort4*)(Vb + ((size_t)((b * NH + h) * HD + d)) * TT + t) = u;
            }
        } else {
            bf16* dst = (which == 0) ? Qb : Kb;
            const float scl = (which == 0) ? 0.125f : 1.0f;
#pragma unroll
            for (int mt = 0; mt < 8; ++mt)
#pragma unroll
                for (int r = 0; r < 4; ++r) {
                    const int m = m0 + wm + mt * 16 + quad * 4 + r;
                    const int b = m >> 11, t = m & (TT - 1);
                    dst[((size_t)(b * NH + h) * TT + t) * HD + d] =
                        f2b((acc[mt][nt][r] + bv) * scl);
                }
        }
    }
}

// ---------------------------------------------------------------------------
// Output projection (MFMA, 128x128 2-phase) -> f32 out.
// ---------------------------------------------------------------------------
__global__ __launch_bounds__(256) void gemm_proj_mfma(
    const bf16* __restrict__ A, const bf16* __restrict__ Bt,
    const float* __restrict__ bias, float* __restrict__ C) {
    __shared__ bf16 Al[128 * 64];
    __shared__ bf16 Bl[128 * 64];
    f32x4 acc[4][4];
    const int m0 = blockIdx.y * 128, n0 = blockIdx.x * 128;
    mfma_gemm_core(A, Bt, m0, n0, acc, Al, Bl);

    const int tid = threadIdx.x, w = tid >> 6, lane = tid & 63;
    const int li = lane & 15, quad = lane >> 4;
    const int wm = (w & 1) * 64, wn = (w >> 1) * 64;

#pragma unroll
    for (int nt = 0; nt < 4; ++nt) {
        const int n = n0 + wn + nt * 16 + li;
        const float bv = bias[n];
#pragma unroll
        for (int mt = 0; mt < 4; ++mt)
#pragma unroll
            for (int r = 0; r < 4; ++r) {
                const int m = m0 + wm + mt * 16 + quad * 4 + r;
                C[(size_t)m * EE + n] = acc[mt][nt][r] + bv;
            }
    }
}

// ---------------------------------------------------------------------------
// MFMA flash attention v7: NO K/V LDS staging, NO barriers. r5 counters
// proved the invariant across 3 grid shapes (46-48us, Occ ~21%, Mfma 14%):
// the per-tile chain {syncthreads+vmcnt(0) drain -> ds_read -> exp -> PV}
// is latency-bound and the 41KB LDS caps occupancy at 3 blocks/CU. K/V is
// L1/L2-resident (256KB per bh), so staging is pure overhead (guide m169).
// Direct per-lane 16B global loads (swizzle algebra: staged-read kf0 ==
// K[(j0+nt*16+li)*64+quad*8]; vf == Vt[(nt*16+li)*TT+j0+ks*32+quad*8]).
// Only per-wave P-tile (2.3KB) stays in LDS; same-wave write->read needs
// only lgkmcnt (compiler-inserted), as in r2. LDS 41->9.2KB: occupancy
// becomes VGPR-bound; waves stream independently; 8 indep kf loads/tile
// pipeline under MFMA. S^T = K Q^T swap, exp no-shift, per-lane l,
// LPT 1-D grid. Q pre-scaled 0.125. Q,K:[B,H,T,64]; V:[B,H,64,T].
// ---------------------------------------------------------------------------
__global__ __launch_bounds__(256) void attn_mfma(
    const bf16* __restrict__ Q, const bf16* __restrict__ K,
    const bf16* __restrict__ Vt, bf16* __restrict__ Y) {
    __shared__ bf16 Pl[4][16 * PPAD];   // per-wave, layout [q=li][key]

    const int tid  = threadIdx.x;
    const int w    = tid >> 6;
    const int lane = tid & 63;
    const int li   = lane & 15;
    const int quad = lane >> 4;
    // global LPT: all longest blocks (qb=31, every bh) dispatch first
    const int idx  = blockIdx.x;
    const int qb   = 31 - (idx >> 5);
    const int bh   = idx & 31;
    const int q0   = qb << 6;
    const int qw0  = q0 + w * 16;

    const bf16* Qb = Q  + (size_t)bh * TT * HD;
    const bf16* Kb = K  + (size_t)bh * TT * HD;
    const bf16* Vb = Vt + (size_t)bh * HD * TT;

    // Q fragments (B-operand; layout identical to A), pre-scaled
    sh8 qf0 = *(const sh8*)(Qb + (size_t)(qw0 + li) * HD + quad * 8);
    sh8 qf1 = *(const sh8*)(Qb + (size_t)(qw0 + li) * HD + 32 + quad * 8);

    f32x4 o[4];
#pragma unroll
    for (int nt = 0; nt < 4; ++nt) o[nt] = (f32x4){0.f, 0.f, 0.f, 0.f};
    float lacc = 0.f;                    // partial l for q = qw0 + li

    const int ntiles = qb + 1;
    for (int it = 0; it < ntiles; ++it) {
        const int j0 = it << 6;
        const bf16* kt = Kb + (size_t)j0 * HD;   // K rows of this tile
        const bf16* vt = Vb + j0;                // V^T cols of this tile
        const bool diag = (it == qb);

        // ---- S^T = K Q^T: row = key (quad*4+r in tile nt), col = q (li) ----
#pragma unroll
        for (int nt = 0; nt < 4; ++nt) {
            f32x4 a = (f32x4){0.f, 0.f, 0.f, 0.f};
            sh8 kf0 = *(const sh8*)(kt + (size_t)(nt * 16 + li) * HD + quad * 8);
            sh8 kf1 = *(const sh8*)(kt + (size_t)(nt * 16 + li) * HD + 32 + quad * 8);
            a = __builtin_amdgcn_mfma_f32_16x16x32_bf16(kf0, qf0, a, 0, 0, 0);
            a = __builtin_amdgcn_mfma_f32_16x16x32_bf16(kf1, qf1, a, 0, 0, 0);

            // p = exp(s) (shift cancels in O/l); causal mask on diagonal tile
            ushort4 u;
            float p0, p1, p2, p3;
            if (diag) {
                const int keyb = j0 + nt * 16 + quad * 4;
                const int qg = qw0 + li;
                p0 = (keyb + 0 > qg) ? 0.f : __expf(a[0]);
                p1 = (keyb + 1 > qg) ? 0.f : __expf(a[1]);
                p2 = (keyb + 2 > qg) ? 0.f : __expf(a[2]);
                p3 = (keyb + 3 > qg) ? 0.f : __expf(a[3]);
            } else {
                p0 = __expf(a[0]); p1 = __expf(a[1]);
                p2 = __expf(a[2]); p3 = __expf(a[3]);
            }
            lacc += (p0 + p1) + (p2 + p3);
            u.x = f2bu(p0); u.y = f2bu(p1); u.z = f2bu(p2); u.w = f2bu(p3);
            // [q=li][key]: 4 consecutive keys -> one b64 write
            *(ushort4*)(&Pl[w][li * PPAD + nt * 16 + quad * 4]) = u;
        }

        // ---- O += P V  (A = P[q=li][key] via ds_read_b128; V direct) ----
#pragma unroll
        for (int ks = 0; ks < 2; ++ks) {
            sh8 pf = *(const sh8*)(&Pl[w][li * PPAD + ks * 32 + quad * 8]);
#pragma unroll
            for (int nt = 0; nt < 4; ++nt) {
                sh8 vf = *(const sh8*)(vt + (size_t)(nt * 16 + li) * TT +
                                       ks * 32 + quad * 8);
                o[nt] = __builtin_amdgcn_mfma_f32_16x16x32_bf16(pf, vf, o[nt], 0, 0, 0);
            }
        }
    }

    // ---- l reduction: sum the 4 quad-lanes sharing this li ----
    lacc += __shfl_xor(lacc, 16, 64);
    lacc += __shfl_xor(lacc, 32, 64);
    // redistribute to C-layout rows: row quad*4+r needs l from lane (quad*4+r)
    float rinv[4];
#pragma unroll
    for (int r = 0; r < 4; ++r)
        rinv[r] = 1.0f / __shfl(lacc, quad * 4 + r, 64);

    const int b = bh >> 4, h = bh & 15;
#pragma unroll
    for (int nt = 0; nt < 4; ++nt)
#pragma unroll
        for (int r = 0; r < 4; ++r) {
            const int q = qw0 + quad * 4 + r;
            Y[((size_t)(b * TT + q)) * EE + h * HD + nt * 16 + li] =
                f2b(o[nt][r] * rinv[r]);
        }
}

// ---------------------------------------------------------------------------
extern "C" void kernel_launch(void* const* d_in, const int* in_sizes, int n_in,
                              void* d_out, int out_size, void* d_ws, size_t ws_size,
                              hipStream_t stream) {
    const float* x      = (const float*)d_in[0];
    const float* w_qkv  = (const float*)d_in[1];
    const float* b_qkv  = (const float*)d_in[2];
    const float* w_proj = (const float*)d_in[3];
    const float* b_proj = (const float*)d_in[4];
    float* out = (float*)d_out;

    const size_t SZ = (size_t)M_ROWS * EE;
    bf16* Q   = (bf16*)d_ws;
    bf16* K   = Q + SZ;
    bf16* V   = K + SZ;
    bf16* XB  = V + SZ;            // x cast; later reused as Y
    bf16* WQT = XB + SZ;           // [3072,1024]
    bf16* WPT = WQT + 3 * SZ / 4;  // [1024,1024]
    bf16* Y   = XB;                // alias: XB dead after gemm_qkv

    // merged prep: 4096 cast blocks + 768 wqkv-transpose + 256 wproj-transpose
    prep<<<dim3(4096 + 768 + 256), dim3(256), 0, stream>>>(
        x, XB, w_qkv, WQT, w_proj, WPT);

    // 8-phase 256x256: grid = (N/256, M/256) = (12, 16), 512 threads
    gemm_qkv_8ph<<<dim3(12, 16), dim3(512), 0, stream>>>(XB, WQT, b_qkv, Q, K, V);

    // barrier-free attention: grid = (T/64) * (B*H) = 1024, 256 threads
    attn_mfma<<<dim3((TT / 64) * (BB * NH)), dim3(256), 0, stream>>>(Q, K, V, Y);

    gemm_proj_mfma<<<dim3(8, 32), dim3(256), 0, stream>>>(Y, WPT, b_proj, out);
}

// Round 7
// 224.454 us; speedup vs baseline: 1.2286x; 1.2286x over previous
//
#include <hip/hip_runtime.h>
#include <hip/hip_bf16.h>

typedef __hip_bfloat16 bf16;
typedef __attribute__((ext_vector_type(8))) short sh8;
typedef __attribute__((ext_vector_type(4))) float f32x4;

// Problem constants
#define BB 2
#define TT 2048
#define EE 1024
#define NH 16
#define HD 64
#define M_ROWS (BB * TT)          // 4096
#define PPAD 72                   // P-tile LDS row stride (elements)

__device__ __forceinline__ float b2f(bf16 v) { return __bfloat162float(v); }
__device__ __forceinline__ bf16 f2b(float v) { return __float2bfloat16(v); }
__device__ __forceinline__ unsigned short f2bu(float v) {
    union { bf16 b; unsigned short u; } x; x.b = f2b(v); return x.u;
}

// async global->LDS, 16B per lane: LDS gets (firstlane base) + lane*16.
__device__ __forceinline__ void gl2lds16(const bf16* g, bf16* l) {
    __builtin_amdgcn_global_load_lds(
        (__attribute__((address_space(1))) void*)g,
        (__attribute__((address_space(3))) void*)l, 16, 0, 0);
}

// ---------------------------------------------------------------------------
// Merged prep: block ranges
//   [0, 4096)        cast x (f32->bf16), 4 elems/thread
//   [4096, 4864)     transpose-cast w_qkv  [1024,3072] -> [3072,1024] bf16
//   [4864, 5120)     transpose-cast w_proj [1024,1024] -> [1024,1024] bf16
// ---------------------------------------------------------------------------
__global__ __launch_bounds__(256) void prep(
    const float* __restrict__ x, bf16* __restrict__ xb,
    const float* __restrict__ Wq, bf16* __restrict__ Wqt,
    const float* __restrict__ Wp, bf16* __restrict__ Wpt) {
    const int bid = blockIdx.x;
    if (bid < 4096) {
        const int i = bid * 256 + threadIdx.x;
        const float4 v = ((const float4*)x)[i];
        ushort4 u;
        u.x = f2bu(v.x); u.y = f2bu(v.y); u.z = f2bu(v.z); u.w = f2bu(v.w);
        ((ushort4*)xb)[i] = u;
        return;
    }
    __shared__ float Ld[64][65];
    const float* src; bf16* dst; int ncols, nc0, kr0;
    if (bid < 4096 + 768) {
        const int t = bid - 4096;
        src = Wq; dst = Wqt; ncols = 3072;
        nc0 = (t % 48) * 64; kr0 = (t / 48) * 64;
    } else {
        const int t = bid - 4096 - 768;
        src = Wp; dst = Wpt; ncols = 1024;
        nc0 = (t % 16) * 64; kr0 = (t / 16) * 64;
    }
#pragma unroll
    for (int i = 0; i < 16; ++i) {
        const int e = threadIdx.x + i * 256;
        Ld[e >> 6][e & 63] = src[(size_t)(kr0 + (e >> 6)) * ncols + nc0 + (e & 63)];
    }
    __syncthreads();
#pragma unroll
    for (int i = 0; i < 16; ++i) {
        const int e = threadIdx.x + i * 256;
        const int r2 = e & 63, c2 = e >> 6;
        dst[(size_t)(nc0 + c2) * EE + kr0 + r2] = f2b(Ld[r2][c2]);
    }
}

// ---------------------------------------------------------------------------
// MFMA GEMM core (128x128 2-phase) -- retained for the output projection.
// ---------------------------------------------------------------------------
__device__ __forceinline__ void mfma_gemm_core(
    const bf16* __restrict__ A, const bf16* __restrict__ Bt,
    int m0, int n0, f32x4 acc[4][4], bf16* Al, bf16* Bl) {
    const int tid = threadIdx.x, w = tid >> 6, lane = tid & 63;
    const int li = lane & 15, quad = lane >> 4;
    const int wm = (w & 1) * 64, wn = (w >> 1) * 64;
    const int srow = w * 32 + (lane >> 3);
    const int scol = (lane & 7) * 8;

#pragma unroll
    for (int mt = 0; mt < 4; ++mt)
#pragma unroll
        for (int nt = 0; nt < 4; ++nt) acc[mt][nt] = (f32x4){0.f, 0.f, 0.f, 0.f};

    for (int k0 = 0; k0 < EE; k0 += 64) {
        __syncthreads();
#pragma unroll
        for (int j = 0; j < 4; ++j) {
            const int row = srow + j * 8;
            const int sk = scol ^ ((row & 7) * 8);
            gl2lds16(A  + (size_t)(m0 + row) * EE + k0 + sk, Al + row * 64 + scol);
            gl2lds16(Bt + (size_t)(n0 + row) * EE + k0 + sk, Bl + row * 64 + scol);
        }
        __syncthreads();
#pragma unroll
        for (int ks = 0; ks < 2; ++ks) {
            const int kof = (ks * 32 + quad * 8) ^ ((li & 7) * 8);
            sh8 af[4], bv[4];
#pragma unroll
            for (int mt = 0; mt < 4; ++mt)
                af[mt] = *(const sh8*)(Al + (wm + mt * 16 + li) * 64 + kof);
#pragma unroll
            for (int nt = 0; nt < 4; ++nt)
                bv[nt] = *(const sh8*)(Bl + (wn + nt * 16 + li) * 64 + kof);
#pragma unroll
            for (int mt = 0; mt < 4; ++mt)
#pragma unroll
                for (int nt = 0; nt < 4; ++nt)
                    acc[mt][nt] = __builtin_amdgcn_mfma_f32_16x16x32_bf16(
                        af[mt], bv[nt], acc[mt][nt], 0, 0, 0);
        }
    }
}

// ---------------------------------------------------------------------------
// QKV GEMM, 8-phase 256x256 schedule (T2 swizzle + T3/T4 counted vmcnt + T5).
// 512 threads = 8 waves (2M x 4N); per-wave 128x64 output (8x4 16x16 frags).
// LDS: 2 dbuf x (A 256x64 + B 256x64) bf16 = 128 KiB. BK=64, 16 K-tiles.
// Zig-zag quadrant order Q00->Q01->Q11->Q10 so each operand half dies one
// phase after load (max live fragments 64 VGPR). Stage slots:
//   p1 A(2i+1,0)  p2 A(2i+1,1)  p3 B(2i+2,0)  p4 B(2i+2,1)+vm4
//   p5 A(2i+2,0)  p6 A(2i+2,1)  p7 B(2i+3,0)  p8 B(2i+3,1)+vm4
// Q is pre-scaled by 0.125 in the epilogue (folded attention scale).
// ---------------------------------------------------------------------------
#define QBM 256
#define QBN 256
#define QBK 64
#define QNT (EE / QBK)   // 16 K-tiles

__global__ __launch_bounds__(512, 2) void gemm_qkv_8ph(
    const bf16* __restrict__ A, const bf16* __restrict__ Bt,
    const float* __restrict__ bias,
    bf16* __restrict__ Qb, bf16* __restrict__ Kb, bf16* __restrict__ Vb) {
    __shared__ bf16 Al[2][QBM * QBK];   // 64 KiB
    __shared__ bf16 Bl[2][QBN * QBK];   // 64 KiB

    const int tid  = threadIdx.x;
    const int lane = tid & 63;
    const int w    = tid >> 6;
    const int li   = lane & 15, quad = lane >> 4;
    const int wr   = w >> 2, wc = w & 3;       // 2 x 4 wave grid
    const int wm   = wr << 7, wn = wc << 6;    // wave origin in tile
    const int m0   = blockIdx.y << 8, n0 = blockIdx.x << 8;

    // staging geometry: thread covers (row = h*128 + j*64 + tid/8, col = (tid&7)*8)
    const int srow = tid >> 3;
    const int scol = (tid & 7) << 3;
    const int sg   = scol ^ ((srow & 7) << 3);   // pre-swizzled global col
    // read-side swizzle
    const int swz  = (li & 7) << 3;
    const int kof0 = (quad << 3) ^ swz;
    const int kof1 = (32 + (quad << 3)) ^ swz;

    f32x4 acc[8][4];
#pragma unroll
    for (int m = 0; m < 8; ++m)
#pragma unroll
        for (int n = 0; n < 4; ++n) acc[m][n] = (f32x4){0.f, 0.f, 0.f, 0.f};

    sh8 ra[4][2];    // current A-half frags (reused half0/half1)
    sh8 rb0[2][2];   // B-half0 frags
    sh8 rb1[2][2];   // B-half1 frags

#define QSTAGE_A(t, h) do {                                                    \
        const int _k0 = (t) * QBK; bf16* _lb = &Al[(t) & 1][0];                \
        _Pragma("unroll")                                                      \
        for (int _j = 0; _j < 2; ++_j) {                                       \
            const int _r = ((h) << 7) + (_j << 6) + srow;                      \
            gl2lds16(A + (size_t)(m0 + _r) * EE + _k0 + sg,                    \
                     _lb + _r * QBK + scol);                                   \
        }                                                                      \
    } while (0)

#define QSTAGE_B(t, h) do {                                                    \
        const int _k0 = (t) * QBK; bf16* _lb = &Bl[(t) & 1][0];                \
        _Pragma("unroll")                                                      \
        for (int _j = 0; _j < 2; ++_j) {                                       \
            const int _r = ((h) << 7) + (_j << 6) + srow;                      \
            gl2lds16(Bt + (size_t)(n0 + _r) * EE + _k0 + sg,                   \
                     _lb + _r * QBK + scol);                                   \
        }                                                                      \
    } while (0)

#define QLOAD_A(cb, a) do {                                                    \
        const bf16* _ab = &Al[cb][0];                                          \
        _Pragma("unroll")                                                      \
        for (int _m = 0; _m < 4; ++_m) {                                       \
            const int _row = wm + (((a) << 2) + _m) * 16 + li;                 \
            ra[_m][0] = *(const sh8*)(_ab + _row * QBK + kof0);                \
            ra[_m][1] = *(const sh8*)(_ab + _row * QBK + kof1);                \
        }                                                                      \
    } while (0)

#define QLOAD_B(cb, b, R) do {                                                 \
        const bf16* _bb = &Bl[cb][0];                                          \
        _Pragma("unroll")                                                      \
        for (int _n = 0; _n < 2; ++_n) {                                       \
            const int _row = wn + (((b) << 1) + _n) * 16 + li;                 \
            R[_n][0] = *(const sh8*)(_bb + _row * QBK + kof0);                 \
            R[_n][1] = *(const sh8*)(_bb + _row * QBK + kof1);                 \
        }                                                                      \
    } while (0)

// one C-quadrant x K=64: 16 MFMA
#define QMFMA(a, b, R) do {                                                    \
        _Pragma("unroll")                                                      \
        for (int _m = 0; _m < 4; ++_m)                                         \
            _Pragma("unroll")                                                  \
            for (int _n = 0; _n < 2; ++_n) {                                   \
                acc[((a) << 2) + _m][((b) << 1) + _n] =                        \
                    __builtin_amdgcn_mfma_f32_16x16x32_bf16(                   \
                        ra[_m][0], R[_n][0],                                   \
                        acc[((a) << 2) + _m][((b) << 1) + _n], 0, 0, 0);       \
                acc[((a) << 2) + _m][((b) << 1) + _n] =                        \
                    __builtin_amdgcn_mfma_f32_16x16x32_bf16(                   \
                        ra[_m][1], R[_n][1],                                   \
                        acc[((a) << 2) + _m][((b) << 1) + _n], 0, 0, 0);       \
            }                                                                  \
    } while (0)

#define PH_MID() do { __builtin_amdgcn_s_barrier();                            \
        asm volatile("s_waitcnt lgkmcnt(0)" ::: "memory");                     \
        __builtin_amdgcn_s_setprio(1); } while (0)
#define PH_END() do { __builtin_amdgcn_s_setprio(0);                           \
        __builtin_amdgcn_s_barrier(); } while (0)
#define PH_END_VM4() do { __builtin_amdgcn_s_setprio(0);                       \
        asm volatile("s_waitcnt vmcnt(4)" ::: "memory");                       \
        __builtin_amdgcn_s_barrier(); } while (0)
#define PH_END_VM0() do { __builtin_amdgcn_s_setprio(0);                       \
        asm volatile("s_waitcnt vmcnt(0)" ::: "memory");                       \
        __builtin_amdgcn_s_barrier(); } while (0)

    // prologue: tile0 A+B (8 loads) + B(1) (4 loads); vm4 => tile0 landed
    QSTAGE_A(0, 0); QSTAGE_A(0, 1); QSTAGE_B(0, 0); QSTAGE_B(0, 1);
    QSTAGE_B(1, 0); QSTAGE_B(1, 1);
    asm volatile("s_waitcnt vmcnt(4)" ::: "memory");
    __builtin_amdgcn_s_barrier();

#pragma unroll 1
    for (int i = 0; i < QNT / 2 - 1; ++i) {
        const int ta = 2 * i + 1, tb = 2 * i + 2, tc = 2 * i + 3;
        // ---- tile 2i (buf0): zig-zag Q00,Q01,Q11,Q10 ----
        QLOAD_A(0, 0); QLOAD_B(0, 0, rb0); QSTAGE_A(ta, 0);   // p1
        PH_MID(); QMFMA(0, 0, rb0); PH_END();
        QLOAD_B(0, 1, rb1); QSTAGE_A(ta, 1);                  // p2
        PH_MID(); QMFMA(0, 1, rb1); PH_END();
        QLOAD_A(0, 1); QSTAGE_B(tb, 0);                       // p3
        PH_MID(); QMFMA(1, 1, rb1); PH_END();
        QSTAGE_B(tb, 1);                                      // p4
        PH_MID(); QMFMA(1, 0, rb0); PH_END_VM4();
        // ---- tile 2i+1 (buf1) ----
        QLOAD_A(1, 0); QLOAD_B(1, 0, rb0); QSTAGE_A(tb, 0);   // p5
        PH_MID(); QMFMA(0, 0, rb0); PH_END();
        QLOAD_B(1, 1, rb1); QSTAGE_A(tb, 1);                  // p6
        PH_MID(); QMFMA(0, 1, rb1); PH_END();
        QLOAD_A(1, 1); QSTAGE_B(tc, 0);                       // p7
        PH_MID(); QMFMA(1, 1, rb1); PH_END();
        QSTAGE_B(tc, 1);                                      // p8
        PH_MID(); QMFMA(1, 0, rb0); PH_END_VM4();
    }

    // epilogue: tile 14 (buf0) staging A(15); tile 15 (buf1), no stages
    QLOAD_A(0, 0); QLOAD_B(0, 0, rb0); QSTAGE_A(QNT - 1, 0);  // p1
    PH_MID(); QMFMA(0, 0, rb0); PH_END();
    QLOAD_B(0, 1, rb1); QSTAGE_A(QNT - 1, 1);                 // p2
    PH_MID(); QMFMA(0, 1, rb1); PH_END();
    QLOAD_A(0, 1);                                            // p3
    PH_MID(); QMFMA(1, 1, rb1); PH_END();
    PH_MID(); QMFMA(1, 0, rb0); PH_END_VM0();                 // p4
    QLOAD_A(1, 0); QLOAD_B(1, 0, rb0);                        // p5
    PH_MID(); QMFMA(0, 0, rb0); PH_END();
    QLOAD_B(1, 1, rb1);                                       // p6
    PH_MID(); QMFMA(0, 1, rb1); PH_END();
    QLOAD_A(1, 1);                                            // p7
    PH_MID(); QMFMA(1, 1, rb1); PH_END();
    PH_MID(); QMFMA(1, 0, rb0);                               // p8
    __builtin_amdgcn_s_setprio(0);

#undef QSTAGE_A
#undef QSTAGE_B
#undef QLOAD_A
#undef QLOAD_B
#undef QMFMA
#undef PH_MID
#undef PH_END
#undef PH_END_VM4
#undef PH_END_VM0

    // ---- C-write: scatter into Q (x0.125), K, or V-transposed ----
    const int which = n0 >> 10;   // 0=Q, 1=K, 2=V (256 | 1024, no straddle)
#pragma unroll
    for (int nt = 0; nt < 4; ++nt) {
        const int n = n0 + wn + nt * 16 + li;
        const int hseg = n & 1023;
        const int h = hseg >> 6, d = hseg & 63;
        const float bv = bias[n];
        if (which == 2) {
#pragma unroll
            for (int mt = 0; mt < 8; ++mt) {
                const int mb = m0 + wm + mt * 16 + quad * 4;
                const int b = mb >> 11, t = mb & (TT - 1);
                ushort4 u;
                u.x = f2bu(acc[mt][nt][0] + bv);
                u.y = f2bu(acc[mt][nt][1] + bv);
                u.z = f2bu(acc[mt][nt][2] + bv);
                u.w = f2bu(acc[mt][nt][3] + bv);
                *(ushort4*)(Vb + ((size_t)((b * NH + h) * HD + d)) * TT + t) = u;
            }
        } else {
            bf16* dst = (which == 0) ? Qb : Kb;
            const float scl = (which == 0) ? 0.125f : 1.0f;
#pragma unroll
            for (int mt = 0; mt < 8; ++mt)
#pragma unroll
                for (int r = 0; r < 4; ++r) {
                    const int m = m0 + wm + mt * 16 + quad * 4 + r;
                    const int b = m >> 11, t = m & (TT - 1);
                    dst[((size_t)(b * NH + h) * TT + t) * HD + d] =
                        f2b((acc[mt][nt][r] + bv) * scl);
                }
        }
    }
}

// ---------------------------------------------------------------------------
// Output projection (MFMA, 128x128 2-phase) -> f32 out.
// ---------------------------------------------------------------------------
__global__ __launch_bounds__(256) void gemm_proj_mfma(
    const bf16* __restrict__ A, const bf16* __restrict__ Bt,
    const float* __restrict__ bias, float* __restrict__ C) {
    __shared__ bf16 Al[128 * 64];
    __shared__ bf16 Bl[128 * 64];
    f32x4 acc[4][4];
    const int m0 = blockIdx.y * 128, n0 = blockIdx.x * 128;
    mfma_gemm_core(A, Bt, m0, n0, acc, Al, Bl);

    const int tid = threadIdx.x, w = tid >> 6, lane = tid & 63;
    const int li = lane & 15, quad = lane >> 4;
    const int wm = (w & 1) * 64, wn = (w >> 1) * 64;

#pragma unroll
    for (int nt = 0; nt < 4; ++nt) {
        const int n = n0 + wn + nt * 16 + li;
        const float bv = bias[n];
#pragma unroll
        for (int mt = 0; mt < 4; ++mt)
#pragma unroll
            for (int r = 0; r < 4; ++r) {
                const int m = m0 + wm + mt * 16 + quad * 4 + r;
                C[(size_t)m * EE + n] = acc[mt][nt][r] + bv;
            }
    }
}

// ---------------------------------------------------------------------------
// MFMA flash attention v8: r2-proven core with ONE asymmetric change.
// r6 proved staging = the prefetch pipeline (direct loads at point-of-use:
// 137us, MfmaUtil 5%); r4/r5 proved 41KB LDS caps occupancy at 3 blocks/CU.
// Split the difference by data role:
//   K: staged + double-buffered via global_load_lds (prefetch of tile it+1
//      overlaps compute of tile it) -- the latency-critical operand, since
//      QK MFMA consumes it immediately after the barrier.
//   V: direct per-lane 16B global loads, ISSUED EARLY (top of iteration,
//      before the QK cluster) into registers -- T14 issue-early/use-late:
//      ~600 cyc of QK+exp hides the L2 latency. Verified address algebra:
//      staged-read vf == Vt[(nt*16+li)*TT + j0 + ks*32 + quad*8].
// LDS: Kl 16K + Pl 9K = 25 KB -> 6 blocks/CU by LDS (VGPR-bound ~4/SIMD),
// vs r2's 3 blocks. Barrier drains 2 staged loads/wave (was 4).
// S^T = K Q^T swap, __expf no-shift (cancels in O/l), per-lane l, LPT grid.
// Q pre-scaled 0.125. Q,K:[B,H,T,64]; V:[B,H,64,T]; Y:[B,T,E] bf16.
// ---------------------------------------------------------------------------
__global__ __launch_bounds__(256) void attn_mfma(
    const bf16* __restrict__ Q, const bf16* __restrict__ K,
    const bf16* __restrict__ Vt, bf16* __restrict__ Y) {
    __shared__ bf16 Kl[2][64 * 64];
    __shared__ bf16 Pl[4][16 * PPAD];   // per-wave, layout [q=li][key]

    const int tid  = threadIdx.x;
    const int w    = tid >> 6;
    const int lane = tid & 63;
    const int li   = lane & 15;
    const int quad = lane >> 4;
    const int swz  = (li & 7) * 8;
    // global LPT: all longest blocks (qb=31, every bh) dispatch first
    const int idx  = blockIdx.x;
    const int qb   = 31 - (idx >> 5);
    const int bh   = idx & 31;
    const int q0   = qb << 6;
    const int qw0  = q0 + w * 16;

    const bf16* Qb = Q  + (size_t)bh * TT * HD;
    const bf16* Kb = K  + (size_t)bh * TT * HD;
    const bf16* Vb = Vt + (size_t)bh * HD * TT;

    // Q fragments (B-operand; layout identical to A), pre-scaled
    sh8 qf0 = *(const sh8*)(Qb + (size_t)(qw0 + li) * HD + quad * 8);
    sh8 qf1 = *(const sh8*)(Qb + (size_t)(qw0 + li) * HD + 32 + quad * 8);

    f32x4 o[4];
#pragma unroll
    for (int nt = 0; nt < 4; ++nt) o[nt] = (f32x4){0.f, 0.f, 0.f, 0.f};
    float lacc = 0.f;                    // partial l for q = qw0 + li

    const int l8 = lane >> 3, l7 = lane & 7;
    const int gcol = ((l7 ^ l8) * 8);    // swizzled source column (K staging)
    // per-lane V base: row (nt*16+li), col quad*8 within tile
    const bf16* vrow = Vb + (size_t)li * TT + quad * 8;

    const int ntiles = qb + 1;
    // prologue: stage K tile 0 into buffer 0 (2 loads/wave: rows w*16..+15)
#pragma unroll
    for (int c = 0; c < 2; ++c) {
        const int rb = w * 16 + c * 8;
        gl2lds16(Kb + (size_t)(rb + l8) * HD + gcol, &Kl[0][rb * 64]);
    }

    for (int it = 0; it < ntiles; ++it) {
        const int cur = it & 1;
        __syncthreads();                 // drains K-stage loads for tile `it`
        if (it + 1 < ntiles) {           // prefetch K tile it+1 (overlaps compute)
            const int j1 = (it + 1) << 6;
            const int nxt = cur ^ 1;
#pragma unroll
            for (int c = 0; c < 2; ++c) {
                const int rb = w * 16 + c * 8;
                gl2lds16(Kb + (size_t)(j1 + rb + l8) * HD + gcol, &Kl[nxt][rb * 64]);
            }
        }
        const int j0 = it << 6;
        const bf16* kb = &Kl[cur][0];

        // ---- V issue-early: both ks batches, hidden under QK + exp ----
        sh8 vf0[4], vf1[4];
#pragma unroll
        for (int nt = 0; nt < 4; ++nt) {
            const bf16* vr = vrow + (size_t)(nt * 16) * TT + j0;
            vf0[nt] = *(const sh8*)(vr);
            vf1[nt] = *(const sh8*)(vr + 32);
        }

        // ---- S^T = K Q^T: row = key (quad*4+r in tile nt), col = q (li) ----
        const bool diag = (it == ntiles - 1);
#pragma unroll
        for (int nt = 0; nt < 4; ++nt) {
            f32x4 a = (f32x4){0.f, 0.f, 0.f, 0.f};
            sh8 kf0 = *(const sh8*)(kb + (nt * 16 + li) * 64 + ((quad * 8) ^ swz));
            a = __builtin_amdgcn_mfma_f32_16x16x32_bf16(kf0, qf0, a, 0, 0, 0);
            sh8 kf1 = *(const sh8*)(kb + (nt * 16 + li) * 64 + ((32 + quad * 8) ^ swz));
            a = __builtin_amdgcn_mfma_f32_16x16x32_bf16(kf1, qf1, a, 0, 0, 0);

            // p = exp(s) (shift cancels in O/l); causal mask on diagonal tile
            ushort4 u;
            float p0, p1, p2, p3;
            if (diag) {
                const int keyb = j0 + nt * 16 + quad * 4;
                const int qg = qw0 + li;
                p0 = (keyb + 0 > qg) ? 0.f : __expf(a[0]);
                p1 = (keyb + 1 > qg) ? 0.f : __expf(a[1]);
                p2 = (keyb + 2 > qg) ? 0.f : __expf(a[2]);
                p3 = (keyb + 3 > qg) ? 0.f : __expf(a[3]);
            } else {
                p0 = __expf(a[0]); p1 = __expf(a[1]);
                p2 = __expf(a[2]); p3 = __expf(a[3]);
            }
            lacc += (p0 + p1) + (p2 + p3);
            u.x = f2bu(p0); u.y = f2bu(p1); u.z = f2bu(p2); u.w = f2bu(p3);
            // [q=li][key]: 4 consecutive keys -> one b64 write
            *(ushort4*)(&Pl[w][li * PPAD + nt * 16 + quad * 4]) = u;
        }

        // ---- O += P V  (A = P[q=li][key] via ds_read_b128; V in regs) ----
        {
            sh8 pf0 = *(const sh8*)(&Pl[w][li * PPAD + quad * 8]);
#pragma unroll
            for (int nt = 0; nt < 4; ++nt)
                o[nt] = __builtin_amdgcn_mfma_f32_16x16x32_bf16(pf0, vf0[nt], o[nt], 0, 0, 0);
            sh8 pf1 = *(const sh8*)(&Pl[w][li * PPAD + 32 + quad * 8]);
#pragma unroll
            for (int nt = 0; nt < 4; ++nt)
                o[nt] = __builtin_amdgcn_mfma_f32_16x16x32_bf16(pf1, vf1[nt], o[nt], 0, 0, 0);
        }
    }

    // ---- l reduction: sum the 4 quad-lanes sharing this li ----
    lacc += __shfl_xor(lacc, 16, 64);
    lacc += __shfl_xor(lacc, 32, 64);
    // redistribute to C-layout rows: row quad*4+r needs l from lane (quad*4+r)
    float rinv[4];
#pragma unroll
    for (int r = 0; r < 4; ++r)
        rinv[r] = 1.0f / __shfl(lacc, quad * 4 + r, 64);

    const int b = bh >> 4, h = bh & 15;
#pragma unroll
    for (int nt = 0; nt < 4; ++nt)
#pragma unroll
        for (int r = 0; r < 4; ++r) {
            const int q = qw0 + quad * 4 + r;
            Y[((size_t)(b * TT + q)) * EE + h * HD + nt * 16 + li] =
                f2b(o[nt][r] * rinv[r]);
        }
}

// ---------------------------------------------------------------------------
extern "C" void kernel_launch(void* const* d_in, const int* in_sizes, int n_in,
                              void* d_out, int out_size, void* d_ws, size_t ws_size,
                              hipStream_t stream) {
    const float* x      = (const float*)d_in[0];
    const float* w_qkv  = (const float*)d_in[1];
    const float* b_qkv  = (const float*)d_in[2];
    const float* w_proj = (const float*)d_in[3];
    const float* b_proj = (const float*)d_in[4];
    float* out = (float*)d_out;

    const size_t SZ = (size_t)M_ROWS * EE;
    bf16* Q   = (bf16*)d_ws;
    bf16* K   = Q + SZ;
    bf16* V   = K + SZ;
    bf16* XB  = V + SZ;            // x cast; later reused as Y
    bf16* WQT = XB + SZ;           // [3072,1024]
    bf16* WPT = WQT + 3 * SZ / 4;  // [1024,1024]
    bf16* Y   = XB;                // alias: XB dead after gemm_qkv

    // merged prep: 4096 cast blocks + 768 wqkv-transpose + 256 wproj-transpose
    prep<<<dim3(4096 + 768 + 256), dim3(256), 0, stream>>>(
        x, XB, w_qkv, WQT, w_proj, WPT);

    // 8-phase 256x256: grid = (N/256, M/256) = (12, 16), 512 threads
    gemm_qkv_8ph<<<dim3(12, 16), dim3(512), 0, stream>>>(XB, WQT, b_qkv, Q, K, V);

    // K-staged / V-direct attention: grid = (T/64) * (B*H) = 1024, 256 thr
    attn_mfma<<<dim3((TT / 64) * (BB * NH)), dim3(256), 0, stream>>>(Q, K, V, Y);

    gemm_proj_mfma<<<dim3(8, 32), dim3(256), 0, stream>>>(Y, WPT, b_proj, out);
}

// Round 8
// 181.016 us; speedup vs baseline: 1.5234x; 1.2400x over previous
//
#include <hip/hip_runtime.h>
#include <hip/hip_bf16.h>

typedef __hip_bfloat16 bf16;
typedef __attribute__((ext_vector_type(8))) short sh8;
typedef __attribute__((ext_vector_type(4))) float f32x4;

// Problem constants
#define BB 2
#define TT 2048
#define EE 1024
#define NH 16
#define HD 64
#define M_ROWS (BB * TT)          // 4096
#define PPAD 72                   // P-tile LDS row stride (elements)

__device__ __forceinline__ float b2f(bf16 v) { return __bfloat162float(v); }
__device__ __forceinline__ bf16 f2b(float v) { return __float2bfloat16(v); }
__device__ __forceinline__ unsigned short f2bu(float v) {
    union { bf16 b; unsigned short u; } x; x.b = f2b(v); return x.u;
}

// async global->LDS, 16B per lane: LDS gets (firstlane base) + lane*16.
__device__ __forceinline__ void gl2lds16(const bf16* g, bf16* l) {
    __builtin_amdgcn_global_load_lds(
        (__attribute__((address_space(1))) void*)g,
        (__attribute__((address_space(3))) void*)l, 16, 0, 0);
}

// ---------------------------------------------------------------------------
// Merged prep: block ranges
//   [0, 4096)        cast x (f32->bf16), 4 elems/thread
//   [4096, 4864)     transpose-cast w_qkv  [1024,3072] -> [3072,1024] bf16
//   [4864, 5120)     transpose-cast w_proj [1024,1024] -> [1024,1024] bf16
// ---------------------------------------------------------------------------
__global__ __launch_bounds__(256) void prep(
    const float* __restrict__ x, bf16* __restrict__ xb,
    const float* __restrict__ Wq, bf16* __restrict__ Wqt,
    const float* __restrict__ Wp, bf16* __restrict__ Wpt) {
    const int bid = blockIdx.x;
    if (bid < 4096) {
        const int i = bid * 256 + threadIdx.x;
        const float4 v = ((const float4*)x)[i];
        ushort4 u;
        u.x = f2bu(v.x); u.y = f2bu(v.y); u.z = f2bu(v.z); u.w = f2bu(v.w);
        ((ushort4*)xb)[i] = u;
        return;
    }
    __shared__ float Ld[64][65];
    const float* src; bf16* dst; int ncols, nc0, kr0;
    if (bid < 4096 + 768) {
        const int t = bid - 4096;
        src = Wq; dst = Wqt; ncols = 3072;
        nc0 = (t % 48) * 64; kr0 = (t / 48) * 64;
    } else {
        const int t = bid - 4096 - 768;
        src = Wp; dst = Wpt; ncols = 1024;
        nc0 = (t % 16) * 64; kr0 = (t / 16) * 64;
    }
#pragma unroll
    for (int i = 0; i < 16; ++i) {
        const int e = threadIdx.x + i * 256;
        Ld[e >> 6][e & 63] = src[(size_t)(kr0 + (e >> 6)) * ncols + nc0 + (e & 63)];
    }
    __syncthreads();
#pragma unroll
    for (int i = 0; i < 16; ++i) {
        const int e = threadIdx.x + i * 256;
        const int r2 = e & 63, c2 = e >> 6;
        dst[(size_t)(nc0 + c2) * EE + kr0 + r2] = f2b(Ld[r2][c2]);
    }
}

// ---------------------------------------------------------------------------
// MFMA GEMM core (128x128 2-phase) -- retained for the output projection.
// ---------------------------------------------------------------------------
__device__ __forceinline__ void mfma_gemm_core(
    const bf16* __restrict__ A, const bf16* __restrict__ Bt,
    int m0, int n0, f32x4 acc[4][4], bf16* Al, bf16* Bl) {
    const int tid = threadIdx.x, w = tid >> 6, lane = tid & 63;
    const int li = lane & 15, quad = lane >> 4;
    const int wm = (w & 1) * 64, wn = (w >> 1) * 64;
    const int srow = w * 32 + (lane >> 3);
    const int scol = (lane & 7) * 8;

#pragma unroll
    for (int mt = 0; mt < 4; ++mt)
#pragma unroll
        for (int nt = 0; nt < 4; ++nt) acc[mt][nt] = (f32x4){0.f, 0.f, 0.f, 0.f};

    for (int k0 = 0; k0 < EE; k0 += 64) {
        __syncthreads();
#pragma unroll
        for (int j = 0; j < 4; ++j) {
            const int row = srow + j * 8;
            const int sk = scol ^ ((row & 7) * 8);
            gl2lds16(A  + (size_t)(m0 + row) * EE + k0 + sk, Al + row * 64 + scol);
            gl2lds16(Bt + (size_t)(n0 + row) * EE + k0 + sk, Bl + row * 64 + scol);
        }
        __syncthreads();
#pragma unroll
        for (int ks = 0; ks < 2; ++ks) {
            const int kof = (ks * 32 + quad * 8) ^ ((li & 7) * 8);
            sh8 af[4], bv[4];
#pragma unroll
            for (int mt = 0; mt < 4; ++mt)
                af[mt] = *(const sh8*)(Al + (wm + mt * 16 + li) * 64 + kof);
#pragma unroll
            for (int nt = 0; nt < 4; ++nt)
                bv[nt] = *(const sh8*)(Bl + (wn + nt * 16 + li) * 64 + kof);
#pragma unroll
            for (int mt = 0; mt < 4; ++mt)
#pragma unroll
                for (int nt = 0; nt < 4; ++nt)
                    acc[mt][nt] = __builtin_amdgcn_mfma_f32_16x16x32_bf16(
                        af[mt], bv[nt], acc[mt][nt], 0, 0, 0);
        }
    }
}

// ---------------------------------------------------------------------------
// QKV GEMM, 8-phase 256x256 schedule (T2 swizzle + T3/T4 counted vmcnt + T5).
// 512 threads = 8 waves (2M x 4N); per-wave 128x64 output (8x4 16x16 frags).
// LDS: 2 dbuf x (A 256x64 + B 256x64) bf16 = 128 KiB. BK=64, 16 K-tiles.
// Zig-zag quadrant order Q00->Q01->Q11->Q10 so each operand half dies one
// phase after load (max live fragments 64 VGPR). Stage slots:
//   p1 A(2i+1,0)  p2 A(2i+1,1)  p3 B(2i+2,0)  p4 B(2i+2,1)+vm4
//   p5 A(2i+2,0)  p6 A(2i+2,1)  p7 B(2i+3,0)  p8 B(2i+3,1)+vm4
// At ~42us this kernel sits at the known plain-HIP ceiling for K=1024
// 256^2+8ph (m248: 848 TF full-grid; we run 192/256 CUs).
// Q is pre-scaled by 0.125 in the epilogue (folded attention scale).
// ---------------------------------------------------------------------------
#define QBM 256
#define QBN 256
#define QBK 64
#define QNT (EE / QBK)   // 16 K-tiles

__global__ __launch_bounds__(512, 2) void gemm_qkv_8ph(
    const bf16* __restrict__ A, const bf16* __restrict__ Bt,
    const float* __restrict__ bias,
    bf16* __restrict__ Qb, bf16* __restrict__ Kb, bf16* __restrict__ Vb) {
    __shared__ bf16 Al[2][QBM * QBK];   // 64 KiB
    __shared__ bf16 Bl[2][QBN * QBK];   // 64 KiB

    const int tid  = threadIdx.x;
    const int lane = tid & 63;
    const int w    = tid >> 6;
    const int li   = lane & 15, quad = lane >> 4;
    const int wr   = w >> 2, wc = w & 3;       // 2 x 4 wave grid
    const int wm   = wr << 7, wn = wc << 6;    // wave origin in tile
    const int m0   = blockIdx.y << 8, n0 = blockIdx.x << 8;

    // staging geometry: thread covers (row = h*128 + j*64 + tid/8, col = (tid&7)*8)
    const int srow = tid >> 3;
    const int scol = (tid & 7) << 3;
    const int sg   = scol ^ ((srow & 7) << 3);   // pre-swizzled global col
    // read-side swizzle
    const int swz  = (li & 7) << 3;
    const int kof0 = (quad << 3) ^ swz;
    const int kof1 = (32 + (quad << 3)) ^ swz;

    f32x4 acc[8][4];
#pragma unroll
    for (int m = 0; m < 8; ++m)
#pragma unroll
        for (int n = 0; n < 4; ++n) acc[m][n] = (f32x4){0.f, 0.f, 0.f, 0.f};

    sh8 ra[4][2];    // current A-half frags (reused half0/half1)
    sh8 rb0[2][2];   // B-half0 frags
    sh8 rb1[2][2];   // B-half1 frags

#define QSTAGE_A(t, h) do {                                                    \
        const int _k0 = (t) * QBK; bf16* _lb = &Al[(t) & 1][0];                \
        _Pragma("unroll")                                                      \
        for (int _j = 0; _j < 2; ++_j) {                                       \
            const int _r = ((h) << 7) + (_j << 6) + srow;                      \
            gl2lds16(A + (size_t)(m0 + _r) * EE + _k0 + sg,                    \
                     _lb + _r * QBK + scol);                                   \
        }                                                                      \
    } while (0)

#define QSTAGE_B(t, h) do {                                                    \
        const int _k0 = (t) * QBK; bf16* _lb = &Bl[(t) & 1][0];                \
        _Pragma("unroll")                                                      \
        for (int _j = 0; _j < 2; ++_j) {                                       \
            const int _r = ((h) << 7) + (_j << 6) + srow;                      \
            gl2lds16(Bt + (size_t)(n0 + _r) * EE + _k0 + sg,                   \
                     _lb + _r * QBK + scol);                                   \
        }                                                                      \
    } while (0)

#define QLOAD_A(cb, a) do {                                                    \
        const bf16* _ab = &Al[cb][0];                                          \
        _Pragma("unroll")                                                      \
        for (int _m = 0; _m < 4; ++_m) {                                       \
            const int _row = wm + (((a) << 2) + _m) * 16 + li;                 \
            ra[_m][0] = *(const sh8*)(_ab + _row * QBK + kof0);                \
            ra[_m][1] = *(const sh8*)(_ab + _row * QBK + kof1);                \
        }                                                                      \
    } while (0)

#define QLOAD_B(cb, b, R) do {                                                 \
        const bf16* _bb = &Bl[cb][0];                                          \
        _Pragma("unroll")                                                      \
        for (int _n = 0; _n < 2; ++_n) {                                       \
            const int _row = wn + (((b) << 1) + _n) * 16 + li;                 \
            R[_n][0] = *(const sh8*)(_bb + _row * QBK + kof0);                 \
            R[_n][1] = *(const sh8*)(_bb + _row * QBK + kof1);                 \
        }                                                                      \
    } while (0)

// one C-quadrant x K=64: 16 MFMA
#define QMFMA(a, b, R) do {                                                    \
        _Pragma("unroll")                                                      \
        for (int _m = 0; _m < 4; ++_m)                                         \
            _Pragma("unroll")                                                  \
            for (int _n = 0; _n < 2; ++_n) {                                   \
                acc[((a) << 2) + _m][((b) << 1) + _n] =                        \
                    __builtin_amdgcn_mfma_f32_16x16x32_bf16(                   \
                        ra[_m][0], R[_n][0],                                   \
                        acc[((a) << 2) + _m][((b) << 1) + _n], 0, 0, 0);       \
                acc[((a) << 2) + _m][((b) << 1) + _n] =                        \
                    __builtin_amdgcn_mfma_f32_16x16x32_bf16(                   \
                        ra[_m][1], R[_n][1],                                   \
                        acc[((a) << 2) + _m][((b) << 1) + _n], 0, 0, 0);       \
            }                                                                  \
    } while (0)

#define PH_MID() do { __builtin_amdgcn_s_barrier();                            \
        asm volatile("s_waitcnt lgkmcnt(0)" ::: "memory");                     \
        __builtin_amdgcn_s_setprio(1); } while (0)
#define PH_END() do { __builtin_amdgcn_s_setprio(0);                           \
        __builtin_amdgcn_s_barrier(); } while (0)
#define PH_END_VM4() do { __builtin_amdgcn_s_setprio(0);                       \
        asm volatile("s_waitcnt vmcnt(4)" ::: "memory");                       \
        __builtin_amdgcn_s_barrier(); } while (0)
#define PH_END_VM0() do { __builtin_amdgcn_s_setprio(0);                       \
        asm volatile("s_waitcnt vmcnt(0)" ::: "memory");                       \
        __builtin_amdgcn_s_barrier(); } while (0)

    // prologue: tile0 A+B (8 loads) + B(1) (4 loads); vm4 => tile0 landed
    QSTAGE_A(0, 0); QSTAGE_A(0, 1); QSTAGE_B(0, 0); QSTAGE_B(0, 1);
    QSTAGE_B(1, 0); QSTAGE_B(1, 1);
    asm volatile("s_waitcnt vmcnt(4)" ::: "memory");
    __builtin_amdgcn_s_barrier();

#pragma unroll 1
    for (int i = 0; i < QNT / 2 - 1; ++i) {
        const int ta = 2 * i + 1, tb = 2 * i + 2, tc = 2 * i + 3;
        // ---- tile 2i (buf0): zig-zag Q00,Q01,Q11,Q10 ----
        QLOAD_A(0, 0); QLOAD_B(0, 0, rb0); QSTAGE_A(ta, 0);   // p1
        PH_MID(); QMFMA(0, 0, rb0); PH_END();
        QLOAD_B(0, 1, rb1); QSTAGE_A(ta, 1);                  // p2
        PH_MID(); QMFMA(0, 1, rb1); PH_END();
        QLOAD_A(0, 1); QSTAGE_B(tb, 0);                       // p3
        PH_MID(); QMFMA(1, 1, rb1); PH_END();
        QSTAGE_B(tb, 1);                                      // p4
        PH_MID(); QMFMA(1, 0, rb0); PH_END_VM4();
        // ---- tile 2i+1 (buf1) ----
        QLOAD_A(1, 0); QLOAD_B(1, 0, rb0); QSTAGE_A(tb, 0);   // p5
        PH_MID(); QMFMA(0, 0, rb0); PH_END();
        QLOAD_B(1, 1, rb1); QSTAGE_A(tb, 1);                  // p6
        PH_MID(); QMFMA(0, 1, rb1); PH_END();
        QLOAD_A(1, 1); QSTAGE_B(tc, 0);                       // p7
        PH_MID(); QMFMA(1, 1, rb1); PH_END();
        QSTAGE_B(tc, 1);                                      // p8
        PH_MID(); QMFMA(1, 0, rb0); PH_END_VM4();
    }

    // epilogue: tile 14 (buf0) staging A(15); tile 15 (buf1), no stages
    QLOAD_A(0, 0); QLOAD_B(0, 0, rb0); QSTAGE_A(QNT - 1, 0);  // p1
    PH_MID(); QMFMA(0, 0, rb0); PH_END();
    QLOAD_B(0, 1, rb1); QSTAGE_A(QNT - 1, 1);                 // p2
    PH_MID(); QMFMA(0, 1, rb1); PH_END();
    QLOAD_A(0, 1);                                            // p3
    PH_MID(); QMFMA(1, 1, rb1); PH_END();
    PH_MID(); QMFMA(1, 0, rb0); PH_END_VM0();                 // p4
    QLOAD_A(1, 0); QLOAD_B(1, 0, rb0);                        // p5
    PH_MID(); QMFMA(0, 0, rb0); PH_END();
    QLOAD_B(1, 1, rb1);                                       // p6
    PH_MID(); QMFMA(0, 1, rb1); PH_END();
    QLOAD_A(1, 1);                                            // p7
    PH_MID(); QMFMA(1, 1, rb1); PH_END();
    PH_MID(); QMFMA(1, 0, rb0);                               // p8
    __builtin_amdgcn_s_setprio(0);

#undef QSTAGE_A
#undef QSTAGE_B
#undef QLOAD_A
#undef QLOAD_B
#undef QMFMA
#undef PH_MID
#undef PH_END
#undef PH_END_VM4
#undef PH_END_VM0

    // ---- C-write: scatter into Q (x0.125), K, or V-transposed ----
    const int which = n0 >> 10;   // 0=Q, 1=K, 2=V (256 | 1024, no straddle)
#pragma unroll
    for (int nt = 0; nt < 4; ++nt) {
        const int n = n0 + wn + nt * 16 + li;
        const int hseg = n & 1023;
        const int h = hseg >> 6, d = hseg & 63;
        const float bv = bias[n];
        if (which == 2) {
#pragma unroll
            for (int mt = 0; mt < 8; ++mt) {
                const int mb = m0 + wm + mt * 16 + quad * 4;
                const int b = mb >> 11, t = mb & (TT - 1);
                ushort4 u;
                u.x = f2bu(acc[mt][nt][0] + bv);
                u.y = f2bu(acc[mt][nt][1] + bv);
                u.z = f2bu(acc[mt][nt][2] + bv);
                u.w = f2bu(acc[mt][nt][3] + bv);
                *(ushort4*)(Vb + ((size_t)((b * NH + h) * HD + d)) * TT + t) = u;
            }
        } else {
            bf16* dst = (which == 0) ? Qb : Kb;
            const float scl = (which == 0) ? 0.125f : 1.0f;
#pragma unroll
            for (int mt = 0; mt < 8; ++mt)
#pragma unroll
                for (int r = 0; r < 4; ++r) {
                    const int m = m0 + wm + mt * 16 + quad * 4 + r;
                    const int b = m >> 11, t = m & (TT - 1);
                    dst[((size_t)(b * NH + h) * TT + t) * HD + d] =
                        f2b((acc[mt][nt][r] + bv) * scl);
                }
        }
    }
}

// ---------------------------------------------------------------------------
// Output projection (MFMA, 128x128 2-phase) -> f32 out.
// ---------------------------------------------------------------------------
__global__ __launch_bounds__(256) void gemm_proj_mfma(
    const bf16* __restrict__ A, const bf16* __restrict__ Bt,
    const float* __restrict__ bias, float* __restrict__ C) {
    __shared__ bf16 Al[128 * 64];
    __shared__ bf16 Bl[128 * 64];
    f32x4 acc[4][4];
    const int m0 = blockIdx.y * 128, n0 = blockIdx.x * 128;
    mfma_gemm_core(A, Bt, m0, n0, acc, Al, Bl);

    const int tid = threadIdx.x, w = tid >> 6, lane = tid & 63;
    const int li = lane & 15, quad = lane >> 4;
    const int wm = (w & 1) * 64, wn = (w >> 1) * 64;

#pragma unroll
    for (int nt = 0; nt < 4; ++nt) {
        const int n = n0 + wn + nt * 16 + li;
        const float bv = bias[n];
#pragma unroll
        for (int mt = 0; mt < 4; ++mt)
#pragma unroll
            for (int r = 0; r < 4; ++r) {
                const int m = m0 + wm + mt * 16 + quad * 4 + r;
                C[(size_t)m * EE + n] = acc[mt][nt][r] + bv;
            }
    }
}

// ---------------------------------------------------------------------------
// MFMA flash attention -- the r2-proven core, restored verbatim (best
// measured total: 180.44us). Structure invariants (each violated by a
// failed experiment r3-r7): (a) K AND V async-staged via global_load_lds,
// double-buffered, prefetch of tile it+1 issued right after the barrier so
// its drain happens a full compute-phase later (r6/r7: breaking this ->
// 137/88us); (b) staged loads shared block-wide, 4/wave (r7: per-wave V
// loads 4x traffic); (c) QBLK=64/256thr/1024 blocks for 3 blocks/CU + LPT
// (r3: 128-row halved block count -> 46.6; r4 swizzle pack: 48.0; r5
// split-K: 45.6). S^T = K Q^T operand swap (P writes are b64), __expf
// without max-shift (cancels in O/l), scalar per-lane l, LPT 1-D grid.
// Q pre-scaled by 0.125. Q,K:[B,H,T,64]; V:[B,H,64,T]; Y:[B,T,E] bf16.
// ---------------------------------------------------------------------------
__global__ __launch_bounds__(256) void attn_mfma(
    const bf16* __restrict__ Q, const bf16* __restrict__ K,
    const bf16* __restrict__ Vt, bf16* __restrict__ Y) {
    __shared__ bf16 Kl[2][64 * 64];
    __shared__ bf16 Vl[2][64 * 64];
    __shared__ bf16 Pl[4][16 * PPAD];   // per-wave, layout [q=li][key]

    const int tid  = threadIdx.x;
    const int w    = tid >> 6;
    const int lane = tid & 63;
    const int li   = lane & 15;
    const int quad = lane >> 4;
    const int swz  = (li & 7) * 8;
    // global LPT: all longest blocks (qb=31, every bh) dispatch first
    const int idx  = blockIdx.x;
    const int qb   = 31 - (idx >> 5);
    const int bh   = idx & 31;
    const int q0   = qb << 6;
    const int qw0  = q0 + w * 16;

    const bf16* Qb = Q  + (size_t)bh * TT * HD;
    const bf16* Kb = K  + (size_t)bh * TT * HD;
    const bf16* Vb = Vt + (size_t)bh * HD * TT;

    // Q fragments (B-operand; layout identical to A), pre-scaled
    sh8 qf0 = *(const sh8*)(Qb + (size_t)(qw0 + li) * HD + quad * 8);
    sh8 qf1 = *(const sh8*)(Qb + (size_t)(qw0 + li) * HD + 32 + quad * 8);

    f32x4 o[4];
#pragma unroll
    for (int nt = 0; nt < 4; ++nt) o[nt] = (f32x4){0.f, 0.f, 0.f, 0.f};
    float lacc = 0.f;                    // partial l for q = qw0 + li

    const int l8 = lane >> 3, l7 = lane & 7;
    const int gcol = ((l7 ^ l8) * 8);    // swizzled source column

    const int ntiles = qb + 1;
    // prologue: stage tile 0 into buffer 0
#pragma unroll
    for (int c = 0; c < 2; ++c) {
        const int rb = w * 16 + c * 8;
        gl2lds16(Kb + (size_t)(rb + l8) * HD + gcol, &Kl[0][rb * 64]);
        gl2lds16(Vb + (size_t)(rb + l8) * TT + gcol, &Vl[0][rb * 64]);
    }

    for (int it = 0; it < ntiles; ++it) {
        const int cur = it & 1;
        __syncthreads();                 // drains loads for tile `it`
        if (it + 1 < ntiles) {           // prefetch tile it+1 (overlaps compute)
            const int j1 = (it + 1) << 6;
            const int nxt = cur ^ 1;
#pragma unroll
            for (int c = 0; c < 2; ++c) {
                const int rb = w * 16 + c * 8;
                gl2lds16(Kb + (size_t)(j1 + rb + l8) * HD + gcol, &Kl[nxt][rb * 64]);
                gl2lds16(Vb + (size_t)(rb + l8) * TT + j1 + gcol, &Vl[nxt][rb * 64]);
            }
        }
        const bf16* kb = &Kl[cur][0];
        const bf16* vb = &Vl[cur][0];

        // ---- S^T = K Q^T: row = key (quad*4+r in tile nt), col = q (li) ----
        const bool diag = (it == ntiles - 1);
#pragma unroll
        for (int nt = 0; nt < 4; ++nt) {
            f32x4 a = (f32x4){0.f, 0.f, 0.f, 0.f};
            sh8 kf0 = *(const sh8*)(kb + (nt * 16 + li) * 64 + ((quad * 8) ^ swz));
            a = __builtin_amdgcn_mfma_f32_16x16x32_bf16(kf0, qf0, a, 0, 0, 0);
            sh8 kf1 = *(const sh8*)(kb + (nt * 16 + li) * 64 + ((32 + quad * 8) ^ swz));
            a = __builtin_amdgcn_mfma_f32_16x16x32_bf16(kf1, qf1, a, 0, 0, 0);

            // p = exp(s) (shift cancels in O/l); causal mask on diagonal tile
            ushort4 u;
            float p0, p1, p2, p3;
            if (diag) {
                const int keyb = q0 + nt * 16 + quad * 4;   // j0 == q0 here
                const int qg = qw0 + li;
                p0 = (keyb + 0 > qg) ? 0.f : __expf(a[0]);
                p1 = (keyb + 1 > qg) ? 0.f : __expf(a[1]);
                p2 = (keyb + 2 > qg) ? 0.f : __expf(a[2]);
                p3 = (keyb + 3 > qg) ? 0.f : __expf(a[3]);
            } else {
                p0 = __expf(a[0]); p1 = __expf(a[1]);
                p2 = __expf(a[2]); p3 = __expf(a[3]);
            }
            lacc += (p0 + p1) + (p2 + p3);
            u.x = f2bu(p0); u.y = f2bu(p1); u.z = f2bu(p2); u.w = f2bu(p3);
            // [q=li][key]: 4 consecutive keys -> one b64 write
            *(ushort4*)(&Pl[w][li * PPAD + nt * 16 + quad * 4]) = u;
        }

        // ---- O += P V  (A = P[q=li][key] via ds_read_b128) ----
#pragma unroll
        for (int ks = 0; ks < 2; ++ks) {
            sh8 pf = *(const sh8*)(&Pl[w][li * PPAD + ks * 32 + quad * 8]);
#pragma unroll
            for (int nt = 0; nt < 4; ++nt) {
                sh8 vf = *(const sh8*)(vb + (nt * 16 + li) * 64 +
                                       ((ks * 32 + quad * 8) ^ swz));
                o[nt] = __builtin_amdgcn_mfma_f32_16x16x32_bf16(pf, vf, o[nt], 0, 0, 0);
            }
        }
    }

    // ---- l reduction: sum the 4 quad-lanes sharing this li ----
    lacc += __shfl_xor(lacc, 16, 64);
    lacc += __shfl_xor(lacc, 32, 64);
    // redistribute to C-layout rows: row quad*4+r needs l from lane (quad*4+r)
    float rinv[4];
#pragma unroll
    for (int r = 0; r < 4; ++r)
        rinv[r] = 1.0f / __shfl(lacc, quad * 4 + r, 64);

    const int b = bh >> 4, h = bh & 15;
#pragma unroll
    for (int nt = 0; nt < 4; ++nt)
#pragma unroll
        for (int r = 0; r < 4; ++r) {
            const int q = qw0 + quad * 4 + r;
            Y[((size_t)(b * TT + q)) * EE + h * HD + nt * 16 + li] =
                f2b(o[nt][r] * rinv[r]);
        }
}

// ---------------------------------------------------------------------------
extern "C" void kernel_launch(void* const* d_in, const int* in_sizes, int n_in,
                              void* d_out, int out_size, void* d_ws, size_t ws_size,
                              hipStream_t stream) {
    const float* x      = (const float*)d_in[0];
    const float* w_qkv  = (const float*)d_in[1];
    const float* b_qkv  = (const float*)d_in[2];
    const float* w_proj = (const float*)d_in[3];
    const float* b_proj = (const float*)d_in[4];
    float* out = (float*)d_out;

    const size_t SZ = (size_t)M_ROWS * EE;
    bf16* Q   = (bf16*)d_ws;
    bf16* K   = Q + SZ;
    bf16* V   = K + SZ;
    bf16* XB  = V + SZ;            // x cast; later reused as Y
    bf16* WQT = XB + SZ;           // [3072,1024]
    bf16* WPT = WQT + 3 * SZ / 4;  // [1024,1024]
    bf16* Y   = XB;                // alias: XB dead after gemm_qkv

    // merged prep: 4096 cast blocks + 768 wqkv-transpose + 256 wproj-transpose
    prep<<<dim3(4096 + 768 + 256), dim3(256), 0, stream>>>(
        x, XB, w_qkv, WQT, w_proj, WPT);

    // 8-phase 256x256: grid = (N/256, M/256) = (12, 16), 512 threads
    gemm_qkv_8ph<<<dim3(12, 16), dim3(512), 0, stream>>>(XB, WQT, b_qkv, Q, K, V);

    // QBLK=64 attention: grid = (T/64) * (B*H) = 32*32 = 1024, 256 threads
    attn_mfma<<<dim3((TT / 64) * (BB * NH)), dim3(256), 0, stream>>>(Q, K, V, Y);

    gemm_proj_mfma<<<dim3(8, 32), dim3(256), 0, stream>>>(Y, WPT, b_proj, out);
}

// Round 10
// 178.536 us; speedup vs baseline: 1.5446x; 1.0139x over previous
//
#include <hip/hip_runtime.h>
#include <hip/hip_bf16.h>

typedef __hip_bfloat16 bf16;
typedef __attribute__((ext_vector_type(8))) short sh8;
typedef __attribute__((ext_vector_type(4))) float f32x4;

// Problem constants
#define BB 2
#define TT 2048
#define EE 1024
#define NH 16
#define HD 64
#define M_ROWS (BB * TT)          // 4096
#define PPAD 72                   // P-tile LDS row stride (elements)

__device__ __forceinline__ float b2f(bf16 v) { return __bfloat162float(v); }
__device__ __forceinline__ bf16 f2b(float v) { return __float2bfloat16(v); }
__device__ __forceinline__ unsigned short f2bu(float v) {
    union { bf16 b; unsigned short u; } x; x.b = f2b(v); return x.u;
}

// async global->LDS, 16B per lane: LDS gets (firstlane base) + lane*16.
__device__ __forceinline__ void gl2lds16(const bf16* g, bf16* l) {
    __builtin_amdgcn_global_load_lds(
        (__attribute__((address_space(1))) void*)g,
        (__attribute__((address_space(3))) void*)l, 16, 0, 0);
}

// ---------------------------------------------------------------------------
// Merged prep: block ranges
//   [0, 4096)        cast x (f32->bf16), 4 elems/thread
//   [4096, 4864)     transpose-cast w_qkv  [1024,3072] -> [3072,1024] bf16
//   [4864, 5120)     transpose-cast w_proj [1024,1024] -> [1024,1024] bf16
// ---------------------------------------------------------------------------
__global__ __launch_bounds__(256) void prep(
    const float* __restrict__ x, bf16* __restrict__ xb,
    const float* __restrict__ Wq, bf16* __restrict__ Wqt,
    const float* __restrict__ Wp, bf16* __restrict__ Wpt) {
    const int bid = blockIdx.x;
    if (bid < 4096) {
        const int i = bid * 256 + threadIdx.x;
        const float4 v = ((const float4*)x)[i];
        ushort4 u;
        u.x = f2bu(v.x); u.y = f2bu(v.y); u.z = f2bu(v.z); u.w = f2bu(v.w);
        ((ushort4*)xb)[i] = u;
        return;
    }
    __shared__ float Ld[64][65];
    const float* src; bf16* dst; int ncols, nc0, kr0;
    if (bid < 4096 + 768) {
        const int t = bid - 4096;
        src = Wq; dst = Wqt; ncols = 3072;
        nc0 = (t % 48) * 64; kr0 = (t / 48) * 64;
    } else {
        const int t = bid - 4096 - 768;
        src = Wp; dst = Wpt; ncols = 1024;
        nc0 = (t % 16) * 64; kr0 = (t / 16) * 64;
    }
#pragma unroll
    for (int i = 0; i < 16; ++i) {
        const int e = threadIdx.x + i * 256;
        Ld[e >> 6][e & 63] = src[(size_t)(kr0 + (e >> 6)) * ncols + nc0 + (e & 63)];
    }
    __syncthreads();
#pragma unroll
    for (int i = 0; i < 16; ++i) {
        const int e = threadIdx.x + i * 256;
        const int r2 = e & 63, c2 = e >> 6;
        dst[(size_t)(nc0 + c2) * EE + kr0 + r2] = f2b(Ld[r2][c2]);
    }
}

// ---------------------------------------------------------------------------
// MFMA GEMM core (128x128 2-phase) -- retained for the output projection.
// ---------------------------------------------------------------------------
__device__ __forceinline__ void mfma_gemm_core(
    const bf16* __restrict__ A, const bf16* __restrict__ Bt,
    int m0, int n0, f32x4 acc[4][4], bf16* Al, bf16* Bl) {
    const int tid = threadIdx.x, w = tid >> 6, lane = tid & 63;
    const int li = lane & 15, quad = lane >> 4;
    const int wm = (w & 1) * 64, wn = (w >> 1) * 64;
    const int srow = w * 32 + (lane >> 3);
    const int scol = (lane & 7) * 8;

#pragma unroll
    for (int mt = 0; mt < 4; ++mt)
#pragma unroll
        for (int nt = 0; nt < 4; ++nt) acc[mt][nt] = (f32x4){0.f, 0.f, 0.f, 0.f};

    for (int k0 = 0; k0 < EE; k0 += 64) {
        __syncthreads();
#pragma unroll
        for (int j = 0; j < 4; ++j) {
            const int row = srow + j * 8;
            const int sk = scol ^ ((row & 7) * 8);
            gl2lds16(A  + (size_t)(m0 + row) * EE + k0 + sk, Al + row * 64 + scol);
            gl2lds16(Bt + (size_t)(n0 + row) * EE + k0 + sk, Bl + row * 64 + scol);
        }
        __syncthreads();
#pragma unroll
        for (int ks = 0; ks < 2; ++ks) {
            const int kof = (ks * 32 + quad * 8) ^ ((li & 7) * 8);
            sh8 af[4], bv[4];
#pragma unroll
            for (int mt = 0; mt < 4; ++mt)
                af[mt] = *(const sh8*)(Al + (wm + mt * 16 + li) * 64 + kof);
#pragma unroll
            for (int nt = 0; nt < 4; ++nt)
                bv[nt] = *(const sh8*)(Bl + (wn + nt * 16 + li) * 64 + kof);
#pragma unroll
            for (int mt = 0; mt < 4; ++mt)
#pragma unroll
                for (int nt = 0; nt < 4; ++nt)
                    acc[mt][nt] = __builtin_amdgcn_mfma_f32_16x16x32_bf16(
                        af[mt], bv[nt], acc[mt][nt], 0, 0, 0);
        }
    }
}

// ---------------------------------------------------------------------------
// QKV GEMM, 8-phase 256(M)x192(N) schedule. Round-10 change: tile N 256->192
// so grid = (3072/192, 4096/256) = (16,16) = 256 blocks = EXACTLY 1/CU (the
// 256^2 version ran 192 blocks, idling 64 CUs for the whole dispatch).
// 512 threads = 8 waves (2M x 4N); per-wave 128x48 output (8x3 16x16 frags).
// LDS: 2 dbuf x (A 256x64 + B 192x64) bf16 = 112 KiB. BK=64, 16 K-tiles.
// B staged as 3x64-row units (1 gl2lds/thread each); A as 2x128-row halves.
// Steady state at each checkpoint: outstanding = B(ta)3 + A(ta)4 + B(tb)3
// = 10 -> vmcnt(3) drains the 7 oldest (exactly the operands read next
// phase), keeps the newest 3 (B of the tile after). Prologue: A(0)4 +
// B(0)3 + B(1)3 = 10 -> vmcnt(3) leaves B(1). Zig-zag quadrants
// {b01(16 MFMA), b2(8)} x {a0,a1}; live frags ra32+rb01(32)+rb2(16)+acc96
// ~= 195 VGPR < 256 cap. Q/K/V boundary (1024) can fall inside a 192-tile:
// `which` is computed per-nt (16-col groups never straddle a multiple-of-16
// boundary -> wave-uniform). Q pre-scaled by 0.125 in the epilogue.
// ---------------------------------------------------------------------------
#define QBM 256
#define QBN 192
#define QBK 64
#define QNT (EE / QBK)   // 16 K-tiles

__global__ __launch_bounds__(512, 2) void gemm_qkv_8ph(
    const bf16* __restrict__ A, const bf16* __restrict__ Bt,
    const float* __restrict__ bias,
    bf16* __restrict__ Qb, bf16* __restrict__ Kb, bf16* __restrict__ Vb) {
    __shared__ bf16 Al[2][QBM * QBK];   // 64 KiB
    __shared__ bf16 Bl[2][QBN * QBK];   // 48 KiB

    const int tid  = threadIdx.x;
    const int lane = tid & 63;
    const int w    = tid >> 6;
    const int li   = lane & 15, quad = lane >> 4;
    const int wr   = w >> 2, wc = w & 3;       // 2 x 4 wave grid
    const int wm   = wr << 7, wn = wc * 48;    // wave origin in tile
    const int m0   = blockIdx.y << 8, n0 = blockIdx.x * QBN;

    // staging geometry: thread covers (row = base + tid/8, col = (tid&7)*8)
    const int srow = tid >> 3;
    const int scol = (tid & 7) << 3;
    const int sg   = scol ^ ((srow & 7) << 3);   // pre-swizzled global col
    // read-side swizzle
    const int swz  = (li & 7) << 3;
    const int kof0 = (quad << 3) ^ swz;
    const int kof1 = (32 + (quad << 3)) ^ swz;

    f32x4 acc[8][3];
#pragma unroll
    for (int m = 0; m < 8; ++m)
#pragma unroll
        for (int n = 0; n < 3; ++n) acc[m][n] = (f32x4){0.f, 0.f, 0.f, 0.f};

    sh8 ra[4][2];     // current A-half frags (reused half0/half1)
    sh8 rb01[2][2];   // B frags nt=0,1
    sh8 rb2[2];       // B frag nt=2

#define QSTAGE_A(t, h) do {                                                    \
        const int _k0 = (t) * QBK; bf16* _lb = &Al[(t) & 1][0];                \
        _Pragma("unroll")                                                      \
        for (int _j = 0; _j < 2; ++_j) {                                       \
            const int _r = ((h) << 7) + (_j << 6) + srow;                      \
            gl2lds16(A + (size_t)(m0 + _r) * EE + _k0 + sg,                    \
                     _lb + _r * QBK + scol);                                   \
        }                                                                      \
    } while (0)

// one 64-row unit (1 gl2lds per thread)
#define QSTAGE_B(t, u) do {                                                    \
        const int _k0 = (t) * QBK; bf16* _lb = &Bl[(t) & 1][0];                \
        const int _r = ((u) << 6) + srow;                                      \
        gl2lds16(Bt + (size_t)(n0 + _r) * EE + _k0 + sg,                       \
                 _lb + _r * QBK + scol);                                       \
    } while (0)

#define QLOAD_A(cb, a) do {                                                    \
        const bf16* _ab = &Al[cb][0];                                          \
        _Pragma("unroll")                                                      \
        for (int _m = 0; _m < 4; ++_m) {                                       \
            const int _row = wm + (((a) << 2) + _m) * 16 + li;                 \
            ra[_m][0] = *(const sh8*)(_ab + _row * QBK + kof0);                \
            ra[_m][1] = *(const sh8*)(_ab + _row * QBK + kof1);                \
        }                                                                      \
    } while (0)

#define QLOAD_B01(cb) do {                                                     \
        const bf16* _bb = &Bl[cb][0];                                          \
        _Pragma("unroll")                                                      \
        for (int _n = 0; _n < 2; ++_n) {                                       \
            const int _row = wn + _n * 16 + li;                                \
            rb01[_n][0] = *(const sh8*)(_bb + _row * QBK + kof0);              \
            rb01[_n][1] = *(const sh8*)(_bb + _row * QBK + kof1);              \
        }                                                                      \
    } while (0)

#define QLOAD_B2(cb) do {                                                      \
        const bf16* _bb = &Bl[cb][0];                                          \
        const int _row = wn + 32 + li;                                         \
        rb2[0] = *(const sh8*)(_bb + _row * QBK + kof0);                       \
        rb2[1] = *(const sh8*)(_bb + _row * QBK + kof1);                       \
    } while (0)

// a-half x nt{0,1}: 16 MFMA
#define QMFMA01(a) do {                                                        \
        _Pragma("unroll")                                                      \
        for (int _m = 0; _m < 4; ++_m)                                         \
            _Pragma("unroll")                                                  \
            for (int _n = 0; _n < 2; ++_n) {                                   \
                acc[((a) << 2) + _m][_n] =                                     \
                    __builtin_amdgcn_mfma_f32_16x16x32_bf16(                   \
                        ra[_m][0], rb01[_n][0], acc[((a) << 2) + _m][_n],      \
                        0, 0, 0);                                              \
                acc[((a) << 2) + _m][_n] =                                     \
                    __builtin_amdgcn_mfma_f32_16x16x32_bf16(                   \
                        ra[_m][1], rb01[_n][1], acc[((a) << 2) + _m][_n],      \
                        0, 0, 0);                                              \
            }                                                                  \
    } while (0)

// a-half x nt{2}: 8 MFMA
#define QMFMA2(a) do {                                                         \
        _Pragma("unroll")                                                      \
        for (int _m = 0; _m < 4; ++_m) {                                       \
            acc[((a) << 2) + _m][2] =                                          \
                __builtin_amdgcn_mfma_f32_16x16x32_bf16(                       \
                    ra[_m][0], rb2[0], acc[((a) << 2) + _m][2], 0, 0, 0);      \
            acc[((a) << 2) + _m][2] =                                          \
                __builtin_amdgcn_mfma_f32_16x16x32_bf16(                       \
                    ra[_m][1], rb2[1], acc[((a) << 2) + _m][2], 0, 0, 0);      \
        }                                                                      \
    } while (0)

#define PH_MID() do { __builtin_amdgcn_s_barrier();                            \
        asm volatile("s_waitcnt lgkmcnt(0)" ::: "memory");                     \
        __builtin_amdgcn_s_setprio(1); } while (0)
#define PH_END() do { __builtin_amdgcn_s_setprio(0);                           \
        __builtin_amdgcn_s_barrier(); } while (0)
#define PH_END_VM3() do { __builtin_amdgcn_s_setprio(0);                       \
        asm volatile("s_waitcnt vmcnt(3)" ::: "memory");                       \
        __builtin_amdgcn_s_barrier(); } while (0)
#define PH_END_VM0() do { __builtin_amdgcn_s_setprio(0);                       \
        asm volatile("s_waitcnt vmcnt(0)" ::: "memory");                       \
        __builtin_amdgcn_s_barrier(); } while (0)

    // prologue: A(0) 4 ops + B(0) 3 + B(1) 3 = 10; vm3 drains A(0)+B(0)
    QSTAGE_A(0, 0); QSTAGE_A(0, 1);
    QSTAGE_B(0, 0); QSTAGE_B(0, 1); QSTAGE_B(0, 2);
    QSTAGE_B(1, 0); QSTAGE_B(1, 1); QSTAGE_B(1, 2);
    asm volatile("s_waitcnt vmcnt(3)" ::: "memory");
    __builtin_amdgcn_s_barrier();

#pragma unroll 1
    for (int i = 0; i < QNT / 2 - 1; ++i) {
        const int ta = 2 * i + 1, tb = 2 * i + 2, tc = 2 * i + 3;
        // ---- tile 2i (buf0): zig-zag (0,b01) (0,b2) (1,b2) (1,b01) ----
        QLOAD_A(0, 0); QLOAD_B01(0); QSTAGE_A(ta, 0);         // p1
        PH_MID(); QMFMA01(0); PH_END();
        QLOAD_B2(0); QSTAGE_A(ta, 1);                         // p2
        PH_MID(); QMFMA2(0); PH_END();
        QLOAD_A(0, 1); QSTAGE_B(tb, 0);                       // p3
        PH_MID(); QMFMA2(1); PH_END();
        QSTAGE_B(tb, 1); QSTAGE_B(tb, 2);                     // p4
        PH_MID(); QMFMA01(1); PH_END_VM3();
        // ---- tile 2i+1 (buf1) ----
        QLOAD_A(1, 0); QLOAD_B01(1); QSTAGE_A(tb, 0);         // p5
        PH_MID(); QMFMA01(0); PH_END();
        QLOAD_B2(1); QSTAGE_A(tb, 1);                         // p6
        PH_MID(); QMFMA2(0); PH_END();
        QLOAD_A(1, 1); QSTAGE_B(tc, 0);                       // p7
        PH_MID(); QMFMA2(1); PH_END();
        QSTAGE_B(tc, 1); QSTAGE_B(tc, 2);                     // p8
        PH_MID(); QMFMA01(1); PH_END_VM3();
    }

    // epilogue: tile 14 (buf0) staging A(15); tile 15 (buf1), no stages
    QLOAD_A(0, 0); QLOAD_B01(0); QSTAGE_A(QNT - 1, 0);        // p1
    PH_MID(); QMFMA01(0); PH_END();
    QLOAD_B2(0); QSTAGE_A(QNT - 1, 1);                        // p2
    PH_MID(); QMFMA2(0); PH_END();
    QLOAD_A(0, 1);                                            // p3
    PH_MID(); QMFMA2(1); PH_END();
    PH_MID(); QMFMA01(1); PH_END_VM0();                       // p4
    QLOAD_A(1, 0); QLOAD_B01(1);                              // p5
    PH_MID(); QMFMA01(0); PH_END();
    QLOAD_B2(1);                                              // p6
    PH_MID(); QMFMA2(0); PH_END();
    QLOAD_A(1, 1);                                            // p7
    PH_MID(); QMFMA2(1); PH_END();
    PH_MID(); QMFMA01(1);                                     // p8
    __builtin_amdgcn_s_setprio(0);

#undef QSTAGE_A
#undef QSTAGE_B
#undef QLOAD_A
#undef QLOAD_B01
#undef QLOAD_B2
#undef QMFMA01
#undef QMFMA2
#undef PH_MID
#undef PH_END
#undef PH_END_VM3
#undef PH_END_VM0

    // ---- C-write: scatter into Q (x0.125), K, or V-transposed.
    // `which` per nt: 16-col groups never straddle the 1024-boundaries.
#pragma unroll
    for (int nt = 0; nt < 3; ++nt) {
        const int n = n0 + wn + nt * 16 + li;
        const int which = n >> 10;
        const int hseg = n & 1023;
        const int h = hseg >> 6, d = hseg & 63;
        const float bv = bias[n];
        if (which == 2) {
#pragma unroll
            for (int mt = 0; mt < 8; ++mt) {
                const int mb = m0 + wm + mt * 16 + quad * 4;
                const int b = mb >> 11, t = mb & (TT - 1);
                ushort4 u;
                u.x = f2bu(acc[mt][nt][0] + bv);
                u.y = f2bu(acc[mt][nt][1] + bv);
                u.z = f2bu(acc[mt][nt][2] + bv);
                u.w = f2bu(acc[mt][nt][3] + bv);
                *(ushort4*)(Vb + ((size_t)((b * NH + h) * HD + d)) * TT + t) = u;
            }
        } else {
            bf16* dst = (which == 0) ? Qb : Kb;
            const float scl = (which == 0) ? 0.125f : 1.0f;
#pragma unroll
            for (int mt = 0; mt < 8; ++mt)
#pragma unroll
                for (int r = 0; r < 4; ++r) {
                    const int m = m0 + wm + mt * 16 + quad * 4 + r;
                    const int b = m >> 11, t = m & (TT - 1);
                    dst[((size_t)(b * NH + h) * TT + t) * HD + d] =
                        f2b((acc[mt][nt][r] + bv) * scl);
                }
        }
    }
}

// ---------------------------------------------------------------------------
// Output projection (MFMA, 128x128 2-phase) -> f32 out.
// ---------------------------------------------------------------------------
__global__ __launch_bounds__(256) void gemm_proj_mfma(
    const bf16* __restrict__ A, const bf16* __restrict__ Bt,
    const float* __restrict__ bias, float* __restrict__ C) {
    __shared__ bf16 Al[128 * 64];
    __shared__ bf16 Bl[128 * 64];
    f32x4 acc[4][4];
    const int m0 = blockIdx.y * 128, n0 = blockIdx.x * 128;
    mfma_gemm_core(A, Bt, m0, n0, acc, Al, Bl);

    const int tid = threadIdx.x, w = tid >> 6, lane = tid & 63;
    const int li = lane & 15, quad = lane >> 4;
    const int wm = (w & 1) * 64, wn = (w >> 1) * 64;

#pragma unroll
    for (int nt = 0; nt < 4; ++nt) {
        const int n = n0 + wn + nt * 16 + li;
        const float bv = bias[n];
#pragma unroll
        for (int mt = 0; mt < 4; ++mt)
#pragma unroll
            for (int r = 0; r < 4; ++r) {
                const int m = m0 + wm + mt * 16 + quad * 4 + r;
                C[(size_t)m * EE + n] = acc[mt][nt][r] + bv;
            }
    }
}

// ---------------------------------------------------------------------------
// MFMA flash attention -- the r2-proven core, verbatim (r8: 181.0us total,
// passed). Structure invariants (each violated by a failed experiment
// r3-r9): (a) K AND V async-staged via global_load_lds, double-buffered,
// prefetch of tile it+1 issued right after the barrier so its drain lands
// a full compute-phase later; (b) staged loads shared block-wide; (c)
// QBLK=64/256thr/1024 blocks + LPT. S^T = K Q^T operand swap, __expf
// without max-shift (cancels in O/l), scalar per-lane l, LPT 1-D grid.
// Q pre-scaled by 0.125. Q,K:[B,H,T,64]; V:[B,H,64,T]; Y:[B,T,E] bf16.
// ---------------------------------------------------------------------------
__global__ __launch_bounds__(256) void attn_mfma(
    const bf16* __restrict__ Q, const bf16* __restrict__ K,
    const bf16* __restrict__ Vt, bf16* __restrict__ Y) {
    __shared__ bf16 Kl[2][64 * 64];
    __shared__ bf16 Vl[2][64 * 64];
    __shared__ bf16 Pl[4][16 * PPAD];   // per-wave, layout [q=li][key]

    const int tid  = threadIdx.x;
    const int w    = tid >> 6;
    const int lane = tid & 63;
    const int li   = lane & 15;
    const int quad = lane >> 4;
    const int swz  = (li & 7) * 8;
    // global LPT: all longest blocks (qb=31, every bh) dispatch first
    const int idx  = blockIdx.x;
    const int qb   = 31 - (idx >> 5);
    const int bh   = idx & 31;
    const int q0   = qb << 6;
    const int qw0  = q0 + w * 16;

    const bf16* Qb = Q  + (size_t)bh * TT * HD;
    const bf16* Kb = K  + (size_t)bh * TT * HD;
    const bf16* Vb = Vt + (size_t)bh * HD * TT;

    // Q fragments (B-operand; layout identical to A), pre-scaled
    sh8 qf0 = *(const sh8*)(Qb + (size_t)(qw0 + li) * HD + quad * 8);
    sh8 qf1 = *(const sh8*)(Qb + (size_t)(qw0 + li) * HD + 32 + quad * 8);

    f32x4 o[4];
#pragma unroll
    for (int nt = 0; nt < 4; ++nt) o[nt] = (f32x4){0.f, 0.f, 0.f, 0.f};
    float lacc = 0.f;                    // partial l for q = qw0 + li

    const int l8 = lane >> 3, l7 = lane & 7;
    const int gcol = ((l7 ^ l8) * 8);    // swizzled source column

    const int ntiles = qb + 1;
    // prologue: stage tile 0 into buffer 0
#pragma unroll
    for (int c = 0; c < 2; ++c) {
        const int rb = w * 16 + c * 8;
        gl2lds16(Kb + (size_t)(rb + l8) * HD + gcol, &Kl[0][rb * 64]);
        gl2lds16(Vb + (size_t)(rb + l8) * TT + gcol, &Vl[0][rb * 64]);
    }

    for (int it = 0; it < ntiles; ++it) {
        const int cur = it & 1;
        __syncthreads();                 // drains loads for tile `it`
        if (it + 1 < ntiles) {           // prefetch tile it+1 (overlaps compute)
            const int j1 = (it + 1) << 6;
            const int nxt = cur ^ 1;
#pragma unroll
            for (int c = 0; c < 2; ++c) {
                const int rb = w * 16 + c * 8;
                gl2lds16(Kb + (size_t)(j1 + rb + l8) * HD + gcol, &Kl[nxt][rb * 64]);
                gl2lds16(Vb + (size_t)(rb + l8) * TT + j1 + gcol, &Vl[nxt][rb * 64]);
            }
        }
        const bf16* kb = &Kl[cur][0];
        const bf16* vb = &Vl[cur][0];

        // ---- S^T = K Q^T: row = key (quad*4+r in tile nt), col = q (li) ----
        const bool diag = (it == ntiles - 1);
#pragma unroll
        for (int nt = 0; nt < 4; ++nt) {
            f32x4 a = (f32x4){0.f, 0.f, 0.f, 0.f};
            sh8 kf0 = *(const sh8*)(kb + (nt * 16 + li) * 64 + ((quad * 8) ^ swz));
            a = __builtin_amdgcn_mfma_f32_16x16x32_bf16(kf0, qf0, a, 0, 0, 0);
            sh8 kf1 = *(const sh8*)(kb + (nt * 16 + li) * 64 + ((32 + quad * 8) ^ swz));
            a = __builtin_amdgcn_mfma_f32_16x16x32_bf16(kf1, qf1, a, 0, 0, 0);

            // p = exp(s) (shift cancels in O/l); causal mask on diagonal tile
            ushort4 u;
            float p0, p1, p2, p3;
            if (diag) {
                const int keyb = q0 + nt * 16 + quad * 4;   // j0 == q0 here
                const int qg = qw0 + li;
                p0 = (keyb + 0 > qg) ? 0.f : __expf(a[0]);
                p1 = (keyb + 1 > qg) ? 0.f : __expf(a[1]);
                p2 = (keyb + 2 > qg) ? 0.f : __expf(a[2]);
                p3 = (keyb + 3 > qg) ? 0.f : __expf(a[3]);
            } else {
                p0 = __expf(a[0]); p1 = __expf(a[1]);
                p2 = __expf(a[2]); p3 = __expf(a[3]);
            }
            lacc += (p0 + p1) + (p2 + p3);
            u.x = f2bu(p0); u.y = f2bu(p1); u.z = f2bu(p2); u.w = f2bu(p3);
            // [q=li][key]: 4 consecutive keys -> one b64 write
            *(ushort4*)(&Pl[w][li * PPAD + nt * 16 + quad * 4]) = u;
        }

        // ---- O += P V  (A = P[q=li][key] via ds_read_b128) ----
#pragma unroll
        for (int ks = 0; ks < 2; ++ks) {
            sh8 pf = *(const sh8*)(&Pl[w][li * PPAD + ks * 32 + quad * 8]);
#pragma unroll
            for (int nt = 0; nt < 4; ++nt) {
                sh8 vf = *(const sh8*)(vb + (nt * 16 + li) * 64 +
                                       ((ks * 32 + quad * 8) ^ swz));
                o[nt] = __builtin_amdgcn_mfma_f32_16x16x32_bf16(pf, vf, o[nt], 0, 0, 0);
            }
        }
    }

    // ---- l reduction: sum the 4 quad-lanes sharing this li ----
    lacc += __shfl_xor(lacc, 16, 64);
    lacc += __shfl_xor(lacc, 32, 64);
    // redistribute to C-layout rows: row quad*4+r needs l from lane (quad*4+r)
    float rinv[4];
#pragma unroll
    for (int r = 0; r < 4; ++r)
        rinv[r] = 1.0f / __shfl(lacc, quad * 4 + r, 64);

    const int b = bh >> 4, h = bh & 15;
#pragma unroll
    for (int nt = 0; nt < 4; ++nt)
#pragma unroll
        for (int r = 0; r < 4; ++r) {
            const int q = qw0 + quad * 4 + r;
            Y[((size_t)(b * TT + q)) * EE + h * HD + nt * 16 + li] =
                f2b(o[nt][r] * rinv[r]);
        }
}

// ---------------------------------------------------------------------------
extern "C" void kernel_launch(void* const* d_in, const int* in_sizes, int n_in,
                              void* d_out, int out_size, void* d_ws, size_t ws_size,
                              hipStream_t stream) {
    const float* x      = (const float*)d_in[0];
    const float* w_qkv  = (const float*)d_in[1];
    const float* b_qkv  = (const float*)d_in[2];
    const float* w_proj = (const float*)d_in[3];
    const float* b_proj = (const float*)d_in[4];
    float* out = (float*)d_out;

    const size_t SZ = (size_t)M_ROWS * EE;
    bf16* Q   = (bf16*)d_ws;
    bf16* K   = Q + SZ;
    bf16* V   = K + SZ;
    bf16* XB  = V + SZ;            // x cast; later reused as Y
    bf16* WQT = XB + SZ;           // [3072,1024]
    bf16* WPT = WQT + 3 * SZ / 4;  // [1024,1024]
    bf16* Y   = XB;                // alias: XB dead after gemm_qkv

    // merged prep: 4096 cast blocks + 768 wqkv-transpose + 256 wproj-transpose
    prep<<<dim3(4096 + 768 + 256), dim3(256), 0, stream>>>(
        x, XB, w_qkv, WQT, w_proj, WPT);

    // 8-phase 256x192: grid = (3072/192, 4096/256) = (16,16) = 256 blocks
    gemm_qkv_8ph<<<dim3(16, 16), dim3(512), 0, stream>>>(XB, WQT, b_qkv, Q, K, V);

    // QBLK=64 attention: grid = (T/64) * (B*H) = 32*32 = 1024, 256 threads
    attn_mfma<<<dim3((TT / 64) * (BB * NH)), dim3(256), 0, stream>>>(Q, K, V, Y);

    gemm_proj_mfma<<<dim3(8, 32), dim3(256), 0, stream>>>(Y, WPT, b_proj, out);
}

// Round 11
// 178.323 us; speedup vs baseline: 1.5464x; 1.0012x over previous
//
#include <hip/hip_runtime.h>
#include <hip/hip_bf16.h>

typedef __hip_bfloat16 bf16;
typedef __attribute__((ext_vector_type(8))) short sh8;
typedef __attribute__((ext_vector_type(4))) float f32x4;

// Problem constants
#define BB 2
#define TT 2048
#define EE 1024
#define NH 16
#define HD 64
#define M_ROWS (BB * TT)          // 4096
#define PPAD 72                   // P-tile LDS row stride (elements)

__device__ __forceinline__ float b2f(bf16 v) { return __bfloat162float(v); }
__device__ __forceinline__ bf16 f2b(float v) { return __float2bfloat16(v); }
__device__ __forceinline__ unsigned short f2bu(float v) {
    union { bf16 b; unsigned short u; } x; x.b = f2b(v); return x.u;
}

// async global->LDS, 16B per lane: LDS gets (firstlane base) + lane*16.
__device__ __forceinline__ void gl2lds16(const bf16* g, bf16* l) {
    __builtin_amdgcn_global_load_lds(
        (__attribute__((address_space(1))) void*)g,
        (__attribute__((address_space(3))) void*)l, 16, 0, 0);
}

// ---------------------------------------------------------------------------
// Merged prep: block ranges
//   [0, 4096)        cast x (f32->bf16), 4 elems/thread
//   [4096, 4864)     transpose-cast w_qkv  [1024,3072] -> [3072,1024] bf16
//   [4864, 5120)     transpose-cast w_proj [1024,1024] -> [1024,1024] bf16
// ---------------------------------------------------------------------------
__global__ __launch_bounds__(256) void prep(
    const float* __restrict__ x, bf16* __restrict__ xb,
    const float* __restrict__ Wq, bf16* __restrict__ Wqt,
    const float* __restrict__ Wp, bf16* __restrict__ Wpt) {
    const int bid = blockIdx.x;
    if (bid < 4096) {
        const int i = bid * 256 + threadIdx.x;
        const float4 v = ((const float4*)x)[i];
        ushort4 u;
        u.x = f2bu(v.x); u.y = f2bu(v.y); u.z = f2bu(v.z); u.w = f2bu(v.w);
        ((ushort4*)xb)[i] = u;
        return;
    }
    __shared__ float Ld[64][65];
    const float* src; bf16* dst; int ncols, nc0, kr0;
    if (bid < 4096 + 768) {
        const int t = bid - 4096;
        src = Wq; dst = Wqt; ncols = 3072;
        nc0 = (t % 48) * 64; kr0 = (t / 48) * 64;
    } else {
        const int t = bid - 4096 - 768;
        src = Wp; dst = Wpt; ncols = 1024;
        nc0 = (t % 16) * 64; kr0 = (t / 16) * 64;
    }
#pragma unroll
    for (int i = 0; i < 16; ++i) {
        const int e = threadIdx.x + i * 256;
        Ld[e >> 6][e & 63] = src[(size_t)(kr0 + (e >> 6)) * ncols + nc0 + (e & 63)];
    }
    __syncthreads();
#pragma unroll
    for (int i = 0; i < 16; ++i) {
        const int e = threadIdx.x + i * 256;
        const int r2 = e & 63, c2 = e >> 6;
        dst[(size_t)(nc0 + c2) * EE + kr0 + r2] = f2b(Ld[r2][c2]);
    }
}

// ---------------------------------------------------------------------------
// MFMA GEMM core (128x128 2-phase) -- retained for the output projection.
// ---------------------------------------------------------------------------
__device__ __forceinline__ void mfma_gemm_core(
    const bf16* __restrict__ A, const bf16* __restrict__ Bt,
    int m0, int n0, f32x4 acc[4][4], bf16* Al, bf16* Bl) {
    const int tid = threadIdx.x, w = tid >> 6, lane = tid & 63;
    const int li = lane & 15, quad = lane >> 4;
    const int wm = (w & 1) * 64, wn = (w >> 1) * 64;
    const int srow = w * 32 + (lane >> 3);
    const int scol = (lane & 7) * 8;

#pragma unroll
    for (int mt = 0; mt < 4; ++mt)
#pragma unroll
        for (int nt = 0; nt < 4; ++nt) acc[mt][nt] = (f32x4){0.f, 0.f, 0.f, 0.f};

    for (int k0 = 0; k0 < EE; k0 += 64) {
        __syncthreads();
#pragma unroll
        for (int j = 0; j < 4; ++j) {
            const int row = srow + j * 8;
            const int sk = scol ^ ((row & 7) * 8);
            gl2lds16(A  + (size_t)(m0 + row) * EE + k0 + sk, Al + row * 64 + scol);
            gl2lds16(Bt + (size_t)(n0 + row) * EE + k0 + sk, Bl + row * 64 + scol);
        }
        __syncthreads();
#pragma unroll
        for (int ks = 0; ks < 2; ++ks) {
            const int kof = (ks * 32 + quad * 8) ^ ((li & 7) * 8);
            sh8 af[4], bv[4];
#pragma unroll
            for (int mt = 0; mt < 4; ++mt)
                af[mt] = *(const sh8*)(Al + (wm + mt * 16 + li) * 64 + kof);
#pragma unroll
            for (int nt = 0; nt < 4; ++nt)
                bv[nt] = *(const sh8*)(Bl + (wn + nt * 16 + li) * 64 + kof);
#pragma unroll
            for (int mt = 0; mt < 4; ++mt)
#pragma unroll
                for (int nt = 0; nt < 4; ++nt)
                    acc[mt][nt] = __builtin_amdgcn_mfma_f32_16x16x32_bf16(
                        af[mt], bv[nt], acc[mt][nt], 0, 0, 0);
        }
    }
}

// ---------------------------------------------------------------------------
// QKV GEMM, 8-phase 256(M)x192(N), grid (16,16) = 256 blocks = 1/CU.
// Round-11 tweak: stage units moved to the EARLIEST legal phase to deepen
// issue->drain slack (r10 analysis: ~1.2k cy/phase vs ~160 cy MFMA -> the
// phase is latency-padded; tightest edge was A(.,1) issued p6, drained p8
// = 2 phases). New slots (queue-sim verified, same 10->3 drain sets):
//   p1 A(ta,0)+A(ta,1)   p3 B(tb,0..2)   p4 vm3   (A slack 3ph, B 5ph)
//   p5 A(tb,0)+A(tb,1)   p7 B(tc,0..2)   p8 vm3
// Legality: A dest buffer's last reads drained prev-p7 lgkm (2 barriers
// before p1); B dest buffer's reads finish p2's lgkm (barrier before p3).
// Zig-zag quadrants {b01(16 MFMA), b2(8)} x {a0,a1}; ~195 VGPR live.
// Q pre-scaled by 0.125*log2(e) (folds attn scale AND exp->exp2).
// ---------------------------------------------------------------------------
#define QBM 256
#define QBN 192
#define QBK 64
#define QNT (EE / QBK)   // 16 K-tiles

__global__ __launch_bounds__(512, 2) void gemm_qkv_8ph(
    const bf16* __restrict__ A, const bf16* __restrict__ Bt,
    const float* __restrict__ bias,
    bf16* __restrict__ Qb, bf16* __restrict__ Kb, bf16* __restrict__ Vb) {
    __shared__ bf16 Al[2][QBM * QBK];   // 64 KiB
    __shared__ bf16 Bl[2][QBN * QBK];   // 48 KiB

    const int tid  = threadIdx.x;
    const int lane = tid & 63;
    const int w    = tid >> 6;
    const int li   = lane & 15, quad = lane >> 4;
    const int wr   = w >> 2, wc = w & 3;       // 2 x 4 wave grid
    const int wm   = wr << 7, wn = wc * 48;    // wave origin in tile
    const int m0   = blockIdx.y << 8, n0 = blockIdx.x * QBN;

    // staging geometry: thread covers (row = base + tid/8, col = (tid&7)*8)
    const int srow = tid >> 3;
    const int scol = (tid & 7) << 3;
    const int sg   = scol ^ ((srow & 7) << 3);   // pre-swizzled global col
    // read-side swizzle
    const int swz  = (li & 7) << 3;
    const int kof0 = (quad << 3) ^ swz;
    const int kof1 = (32 + (quad << 3)) ^ swz;

    f32x4 acc[8][3];
#pragma unroll
    for (int m = 0; m < 8; ++m)
#pragma unroll
        for (int n = 0; n < 3; ++n) acc[m][n] = (f32x4){0.f, 0.f, 0.f, 0.f};

    sh8 ra[4][2];     // current A-half frags (reused half0/half1)
    sh8 rb01[2][2];   // B frags nt=0,1
    sh8 rb2[2];       // B frag nt=2

#define QSTAGE_A(t, h) do {                                                    \
        const int _k0 = (t) * QBK; bf16* _lb = &Al[(t) & 1][0];                \
        _Pragma("unroll")                                                      \
        for (int _j = 0; _j < 2; ++_j) {                                       \
            const int _r = ((h) << 7) + (_j << 6) + srow;                      \
            gl2lds16(A + (size_t)(m0 + _r) * EE + _k0 + sg,                    \
                     _lb + _r * QBK + scol);                                   \
        }                                                                      \
    } while (0)

// one 64-row unit (1 gl2lds per thread)
#define QSTAGE_B(t, u) do {                                                    \
        const int _k0 = (t) * QBK; bf16* _lb = &Bl[(t) & 1][0];                \
        const int _r = ((u) << 6) + srow;                                      \
        gl2lds16(Bt + (size_t)(n0 + _r) * EE + _k0 + sg,                       \
                 _lb + _r * QBK + scol);                                       \
    } while (0)

#define QLOAD_A(cb, a) do {                                                    \
        const bf16* _ab = &Al[cb][0];                                          \
        _Pragma("unroll")                                                      \
        for (int _m = 0; _m < 4; ++_m) {                                       \
            const int _row = wm + (((a) << 2) + _m) * 16 + li;                 \
            ra[_m][0] = *(const sh8*)(_ab + _row * QBK + kof0);                \
            ra[_m][1] = *(const sh8*)(_ab + _row * QBK + kof1);                \
        }                                                                      \
    } while (0)

#define QLOAD_B01(cb) do {                                                     \
        const bf16* _bb = &Bl[cb][0];                                          \
        _Pragma("unroll")                                                      \
        for (int _n = 0; _n < 2; ++_n) {                                       \
            const int _row = wn + _n * 16 + li;                                \
            rb01[_n][0] = *(const sh8*)(_bb + _row * QBK + kof0);              \
            rb01[_n][1] = *(const sh8*)(_bb + _row * QBK + kof1);              \
        }                                                                      \
    } while (0)

#define QLOAD_B2(cb) do {                                                      \
        const bf16* _bb = &Bl[cb][0];                                          \
        const int _row = wn + 32 + li;                                         \
        rb2[0] = *(const sh8*)(_bb + _row * QBK + kof0);                       \
        rb2[1] = *(const sh8*)(_bb + _row * QBK + kof1);                       \
    } while (0)

// a-half x nt{0,1}: 16 MFMA
#define QMFMA01(a) do {                                                        \
        _Pragma("unroll")                                                      \
        for (int _m = 0; _m < 4; ++_m)                                         \
            _Pragma("unroll")                                                  \
            for (int _n = 0; _n < 2; ++_n) {                                   \
                acc[((a) << 2) + _m][_n] =                                     \
                    __builtin_amdgcn_mfma_f32_16x16x32_bf16(                   \
                        ra[_m][0], rb01[_n][0], acc[((a) << 2) + _m][_n],      \
                        0, 0, 0);                                              \
                acc[((a) << 2) + _m][_n] =                                     \
                    __builtin_amdgcn_mfma_f32_16x16x32_bf16(                   \
                        ra[_m][1], rb01[_n][1], acc[((a) << 2) + _m][_n],      \
                        0, 0, 0);                                              \
            }                                                                  \
    } while (0)

// a-half x nt{2}: 8 MFMA
#define QMFMA2(a) do {                                                         \
        _Pragma("unroll")                                                      \
        for (int _m = 0; _m < 4; ++_m) {                                       \
            acc[((a) << 2) + _m][2] =                                          \
                __builtin_amdgcn_mfma_f32_16x16x32_bf16(                       \
                    ra[_m][0], rb2[0], acc[((a) << 2) + _m][2], 0, 0, 0);      \
            acc[((a) << 2) + _m][2] =                                          \
                __builtin_amdgcn_mfma_f32_16x16x32_bf16(                       \
                    ra[_m][1], rb2[1], acc[((a) << 2) + _m][2], 0, 0, 0);      \
        }                                                                      \
    } while (0)

#define PH_MID() do { __builtin_amdgcn_s_barrier();                            \
        asm volatile("s_waitcnt lgkmcnt(0)" ::: "memory");                     \
        __builtin_amdgcn_s_setprio(1); } while (0)
#define PH_END() do { __builtin_amdgcn_s_setprio(0);                           \
        __builtin_amdgcn_s_barrier(); } while (0)
#define PH_END_VM3() do { __builtin_amdgcn_s_setprio(0);                       \
        asm volatile("s_waitcnt vmcnt(3)" ::: "memory");                       \
        __builtin_amdgcn_s_barrier(); } while (0)
#define PH_END_VM0() do { __builtin_amdgcn_s_setprio(0);                       \
        asm volatile("s_waitcnt vmcnt(0)" ::: "memory");                       \
        __builtin_amdgcn_s_barrier(); } while (0)

    // prologue: A(0) 4 ops + B(0) 3 + B(1) 3 = 10; vm3 drains A(0)+B(0)
    QSTAGE_A(0, 0); QSTAGE_A(0, 1);
    QSTAGE_B(0, 0); QSTAGE_B(0, 1); QSTAGE_B(0, 2);
    QSTAGE_B(1, 0); QSTAGE_B(1, 1); QSTAGE_B(1, 2);
    asm volatile("s_waitcnt vmcnt(3)" ::: "memory");
    __builtin_amdgcn_s_barrier();

#pragma unroll 1
    for (int i = 0; i < QNT / 2 - 1; ++i) {
        const int ta = 2 * i + 1, tb = 2 * i + 2, tc = 2 * i + 3;
        // ---- tile 2i (buf0): zig-zag (0,b01) (0,b2) (1,b2) (1,b01) ----
        QLOAD_A(0, 0); QLOAD_B01(0); QSTAGE_A(ta, 0); QSTAGE_A(ta, 1);  // p1
        PH_MID(); QMFMA01(0); PH_END();
        QLOAD_B2(0);                                                    // p2
        PH_MID(); QMFMA2(0); PH_END();
        QLOAD_A(0, 1); QSTAGE_B(tb, 0); QSTAGE_B(tb, 1); QSTAGE_B(tb, 2); // p3
        PH_MID(); QMFMA2(1); PH_END();
        PH_MID(); QMFMA01(1); PH_END_VM3();                             // p4
        // ---- tile 2i+1 (buf1) ----
        QLOAD_A(1, 0); QLOAD_B01(1); QSTAGE_A(tb, 0); QSTAGE_A(tb, 1);  // p5
        PH_MID(); QMFMA01(0); PH_END();
        QLOAD_B2(1);                                                    // p6
        PH_MID(); QMFMA2(0); PH_END();
        QLOAD_A(1, 1); QSTAGE_B(tc, 0); QSTAGE_B(tc, 1); QSTAGE_B(tc, 2); // p7
        PH_MID(); QMFMA2(1); PH_END();
        PH_MID(); QMFMA01(1); PH_END_VM3();                             // p8
    }

    // epilogue: tile 14 (buf0) staging A(15); tile 15 (buf1), no stages
    QLOAD_A(0, 0); QLOAD_B01(0); QSTAGE_A(QNT - 1, 0); QSTAGE_A(QNT - 1, 1); // p1
    PH_MID(); QMFMA01(0); PH_END();
    QLOAD_B2(0);                                              // p2
    PH_MID(); QMFMA2(0); PH_END();
    QLOAD_A(0, 1);                                            // p3
    PH_MID(); QMFMA2(1); PH_END();
    PH_MID(); QMFMA01(1); PH_END_VM0();                       // p4
    QLOAD_A(1, 0); QLOAD_B01(1);                              // p5
    PH_MID(); QMFMA01(0); PH_END();
    QLOAD_B2(1);                                              // p6
    PH_MID(); QMFMA2(0); PH_END();
    QLOAD_A(1, 1);                                            // p7
    PH_MID(); QMFMA2(1); PH_END();
    PH_MID(); QMFMA01(1);                                     // p8
    __builtin_amdgcn_s_setprio(0);

#undef QSTAGE_A
#undef QSTAGE_B
#undef QLOAD_A
#undef QLOAD_B01
#undef QLOAD_B2
#undef QMFMA01
#undef QMFMA2
#undef PH_MID
#undef PH_END
#undef PH_END_VM3
#undef PH_END_VM0

    // ---- C-write: scatter into Q (x0.125*log2e), K, or V-transposed.
    // `which` per nt: 16-col groups never straddle the 1024-boundaries.
#pragma unroll
    for (int nt = 0; nt < 3; ++nt) {
        const int n = n0 + wn + nt * 16 + li;
        const int which = n >> 10;
        const int hseg = n & 1023;
        const int h = hseg >> 6, d = hseg & 63;
        const float bv = bias[n];
        if (which == 2) {
#pragma unroll
            for (int mt = 0; mt < 8; ++mt) {
                const int mb = m0 + wm + mt * 16 + quad * 4;
                const int b = mb >> 11, t = mb & (TT - 1);
                ushort4 u;
                u.x = f2bu(acc[mt][nt][0] + bv);
                u.y = f2bu(acc[mt][nt][1] + bv);
                u.z = f2bu(acc[mt][nt][2] + bv);
                u.w = f2bu(acc[mt][nt][3] + bv);
                *(ushort4*)(Vb + ((size_t)((b * NH + h) * HD + d)) * TT + t) = u;
            }
        } else {
            bf16* dst = (which == 0) ? Qb : Kb;
            // Q scale = 0.125 (1/sqrt(64)) * log2(e): attention uses exp2
            const float scl = (which == 0) ? 0.18033688f : 1.0f;
#pragma unroll
            for (int mt = 0; mt < 8; ++mt)
#pragma unroll
                for (int r = 0; r < 4; ++r) {
                    const int m = m0 + wm + mt * 16 + quad * 4 + r;
                    const int b = m >> 11, t = m & (TT - 1);
                    dst[((size_t)(b * NH + h) * TT + t) * HD + d] =
                        f2b((acc[mt][nt][r] + bv) * scl);
                }
        }
    }
}

// ---------------------------------------------------------------------------
// Output projection (MFMA, 128x128 2-phase) -> f32 out.
// ---------------------------------------------------------------------------
__global__ __launch_bounds__(256) void gemm_proj_mfma(
    const bf16* __restrict__ A, const bf16* __restrict__ Bt,
    const float* __restrict__ bias, float* __restrict__ C) {
    __shared__ bf16 Al[128 * 64];
    __shared__ bf16 Bl[128 * 64];
    f32x4 acc[4][4];
    const int m0 = blockIdx.y * 128, n0 = blockIdx.x * 128;
    mfma_gemm_core(A, Bt, m0, n0, acc, Al, Bl);

    const int tid = threadIdx.x, w = tid >> 6, lane = tid & 63;
    const int li = lane & 15, quad = lane >> 4;
    const int wm = (w & 1) * 64, wn = (w >> 1) * 64;

#pragma unroll
    for (int nt = 0; nt < 4; ++nt) {
        const int n = n0 + wn + nt * 16 + li;
        const float bv = bias[n];
#pragma unroll
        for (int mt = 0; mt < 4; ++mt)
#pragma unroll
            for (int r = 0; r < 4; ++r) {
                const int m = m0 + wm + mt * 16 + quad * 4 + r;
                C[(size_t)m * EE + n] = acc[mt][nt][r] + bv;
            }
    }
}

// ---------------------------------------------------------------------------
// MFMA flash attention -- the r2-proven core; ONLY change vs r8/r10: __expf
// -> exp2f (the 0.125*log2e scale is folded into Q by the qkv epilogue),
// which removes the hidden x*log2e v_mul inside each __expf from the hot
// VALU phase. Structure invariants (each violated by a failed experiment
// r3-r9): (a) K AND V async-staged via global_load_lds, double-buffered,
// prefetch of tile it+1 issued right after the barrier; (b) staged loads
// shared block-wide; (c) QBLK=64/256thr/1024 blocks + LPT. S^T = K Q^T
// operand swap, no max-shift (cancels in O/l), scalar per-lane l.
// Q,K:[B,H,T,64]; V:[B,H,64,T]; Y:[B,T,E] bf16.
// ---------------------------------------------------------------------------
__global__ __launch_bounds__(256) void attn_mfma(
    const bf16* __restrict__ Q, const bf16* __restrict__ K,
    const bf16* __restrict__ Vt, bf16* __restrict__ Y) {
    __shared__ bf16 Kl[2][64 * 64];
    __shared__ bf16 Vl[2][64 * 64];
    __shared__ bf16 Pl[4][16 * PPAD];   // per-wave, layout [q=li][key]

    const int tid  = threadIdx.x;
    const int w    = tid >> 6;
    const int lane = tid & 63;
    const int li   = lane & 15;
    const int quad = lane >> 4;
    const int swz  = (li & 7) * 8;
    // global LPT: all longest blocks (qb=31, every bh) dispatch first
    const int idx  = blockIdx.x;
    const int qb   = 31 - (idx >> 5);
    const int bh   = idx & 31;
    const int q0   = qb << 6;
    const int qw0  = q0 + w * 16;

    const bf16* Qb = Q  + (size_t)bh * TT * HD;
    const bf16* Kb = K  + (size_t)bh * TT * HD;
    const bf16* Vb = Vt + (size_t)bh * HD * TT;

    // Q fragments (B-operand; layout identical to A), pre-scaled
    sh8 qf0 = *(const sh8*)(Qb + (size_t)(qw0 + li) * HD + quad * 8);
    sh8 qf1 = *(const sh8*)(Qb + (size_t)(qw0 + li) * HD + 32 + quad * 8);

    f32x4 o[4];
#pragma unroll
    for (int nt = 0; nt < 4; ++nt) o[nt] = (f32x4){0.f, 0.f, 0.f, 0.f};
    float lacc = 0.f;                    // partial l for q = qw0 + li

    const int l8 = lane >> 3, l7 = lane & 7;
    const int gcol = ((l7 ^ l8) * 8);    // swizzled source column

    const int ntiles = qb + 1;
    // prologue: stage tile 0 into buffer 0
#pragma unroll
    for (int c = 0; c < 2; ++c) {
        const int rb = w * 16 + c * 8;
        gl2lds16(Kb + (size_t)(rb + l8) * HD + gcol, &Kl[0][rb * 64]);
        gl2lds16(Vb + (size_t)(rb + l8) * TT + gcol, &Vl[0][rb * 64]);
    }

    for (int it = 0; it < ntiles; ++it) {
        const int cur = it & 1;
        __syncthreads();                 // drains loads for tile `it`
        if (it + 1 < ntiles) {           // prefetch tile it+1 (overlaps compute)
            const int j1 = (it + 1) << 6;
            const int nxt = cur ^ 1;
#pragma unroll
            for (int c = 0; c < 2; ++c) {
                const int rb = w * 16 + c * 8;
                gl2lds16(Kb + (size_t)(j1 + rb + l8) * HD + gcol, &Kl[nxt][rb * 64]);
                gl2lds16(Vb + (size_t)(rb + l8) * TT + j1 + gcol, &Vl[nxt][rb * 64]);
            }
        }
        const bf16* kb = &Kl[cur][0];
        const bf16* vb = &Vl[cur][0];

        // ---- S^T = K Q^T: row = key (quad*4+r in tile nt), col = q (li) ----
        const bool diag = (it == ntiles - 1);
#pragma unroll
        for (int nt = 0; nt < 4; ++nt) {
            f32x4 a = (f32x4){0.f, 0.f, 0.f, 0.f};
            sh8 kf0 = *(const sh8*)(kb + (nt * 16 + li) * 64 + ((quad * 8) ^ swz));
            a = __builtin_amdgcn_mfma_f32_16x16x32_bf16(kf0, qf0, a, 0, 0, 0);
            sh8 kf1 = *(const sh8*)(kb + (nt * 16 + li) * 64 + ((32 + quad * 8) ^ swz));
            a = __builtin_amdgcn_mfma_f32_16x16x32_bf16(kf1, qf1, a, 0, 0, 0);

            // p = exp2(s) (Q carries log2e; shift cancels in O/l); causal mask
            ushort4 u;
            float p0, p1, p2, p3;
            if (diag) {
                const int keyb = q0 + nt * 16 + quad * 4;   // j0 == q0 here
                const int qg = qw0 + li;
                p0 = (keyb + 0 > qg) ? 0.f : exp2f(a[0]);
                p1 = (keyb + 1 > qg) ? 0.f : exp2f(a[1]);
                p2 = (keyb + 2 > qg) ? 0.f : exp2f(a[2]);
                p3 = (keyb + 3 > qg) ? 0.f : exp2f(a[3]);
            } else {
                p0 = exp2f(a[0]); p1 = exp2f(a[1]);
                p2 = exp2f(a[2]); p3 = exp2f(a[3]);
            }
            lacc += (p0 + p1) + (p2 + p3);
            u.x = f2bu(p0); u.y = f2bu(p1); u.z = f2bu(p2); u.w = f2bu(p3);
            // [q=li][key]: 4 consecutive keys -> one b64 write
            *(ushort4*)(&Pl[w][li * PPAD + nt * 16 + quad * 4]) = u;
        }

        // ---- O += P V  (A = P[q=li][key] via ds_read_b128) ----
#pragma unroll
        for (int ks = 0; ks < 2; ++ks) {
            sh8 pf = *(const sh8*)(&Pl[w][li * PPAD + ks * 32 + quad * 8]);
#pragma unroll
            for (int nt = 0; nt < 4; ++nt) {
                sh8 vf = *(const sh8*)(vb + (nt * 16 + li) * 64 +
                                       ((ks * 32 + quad * 8) ^ swz));
                o[nt] = __builtin_amdgcn_mfma_f32_16x16x32_bf16(pf, vf, o[nt], 0, 0, 0);
            }
        }
    }

    // ---- l reduction: sum the 4 quad-lanes sharing this li ----
    lacc += __shfl_xor(lacc, 16, 64);
    lacc += __shfl_xor(lacc, 32, 64);
    // redistribute to C-layout rows: row quad*4+r needs l from lane (quad*4+r)
    float rinv[4];
#pragma unroll
    for (int r = 0; r < 4; ++r)
        rinv[r] = 1.0f / __shfl(lacc, quad * 4 + r, 64);

    const int b = bh >> 4, h = bh & 15;
#pragma unroll
    for (int nt = 0; nt < 4; ++nt)
#pragma unroll
        for (int r = 0; r < 4; ++r) {
            const int q = qw0 + quad * 4 + r;
            Y[((size_t)(b * TT + q)) * EE + h * HD + nt * 16 + li] =
                f2b(o[nt][r] * rinv[r]);
        }
}

// ---------------------------------------------------------------------------
extern "C" void kernel_launch(void* const* d_in, const int* in_sizes, int n_in,
                              void* d_out, int out_size, void* d_ws, size_t ws_size,
                              hipStream_t stream) {
    const float* x      = (const float*)d_in[0];
    const float* w_qkv  = (const float*)d_in[1];
    const float* b_qkv  = (const float*)d_in[2];
    const float* w_proj = (const float*)d_in[3];
    const float* b_proj = (const float*)d_in[4];
    float* out = (float*)d_out;

    const size_t SZ = (size_t)M_ROWS * EE;
    bf16* Q   = (bf16*)d_ws;
    bf16* K   = Q + SZ;
    bf16* V   = K + SZ;
    bf16* XB  = V + SZ;            // x cast; later reused as Y
    bf16* WQT = XB + SZ;           // [3072,1024]
    bf16* WPT = WQT + 3 * SZ / 4;  // [1024,1024]
    bf16* Y   = XB;                // alias: XB dead after gemm_qkv

    // merged prep: 4096 cast blocks + 768 wqkv-transpose + 256 wproj-transpose
    prep<<<dim3(4096 + 768 + 256), dim3(256), 0, stream>>>(
        x, XB, w_qkv, WQT, w_proj, WPT);

    // 8-phase 256x192: grid = (3072/192, 4096/256) = (16,16) = 256 blocks
    gemm_qkv_8ph<<<dim3(16, 16), dim3(512), 0, stream>>>(XB, WQT, b_qkv, Q, K, V);

    // QBLK=64 attention: grid = (T/64) * (B*H) = 32*32 = 1024, 256 threads
    attn_mfma<<<dim3((TT / 64) * (BB * NH)), dim3(256), 0, stream>>>(Q, K, V, Y);

    gemm_proj_mfma<<<dim3(8, 32), dim3(256), 0, stream>>>(Y, WPT, b_proj, out);
}